// Round 11
// baseline (326.013 us; speedup 1.0000x reference)
//
#include <hip/hip_runtime.h>
#include <math.h>

// Problem constants
#define T_DIM 16
#define B_DIM 128
#define N_DIM 2048
#define TB    (T_DIM * B_DIM)   // 2048 rows of the GEMM

// d_ws layout (bytes): h f32 16MB | psum 0.5MB | psum2 0.5MB | ssum 16KB
#define WS_H      0
#define WS_PSUM   16777216
#define WS_PSUM2  17301504
#define WS_SSUM   17825792

typedef __attribute__((ext_vector_type(8))) short short8;
typedef __attribute__((ext_vector_type(4))) float f32x4;

// bf16 split planes: [x0,x1,x2,W0,W1,W2], each [2048][2048] bf16 = 8MB.
// Static device global (module-load allocation; not hipMalloc -> graph-safe).
#define PLANE 4194304ull
__device__ __align__(16) unsigned short g_planes[6ull * PLANE];

// ---- probe helpers (asymmetric integer patterns, exact in bf16/f32) -------
__device__ __forceinline__ double probeA(int m, int k) {
    return (double)((m * 7 + k * 13) % 23 - 11);
}
__device__ __forceinline__ double probeB(int k, int n) {
    return (double)((k * 5 + n * 3) % 19 - 9);
}

// round-to-nearest-even f32 -> bf16; returns bits, writes back-converted f32
__device__ __forceinline__ unsigned bf16_rne(float f, float* back) {
    unsigned u = __float_as_uint(f);
    unsigned r = u + 0x7FFFu + ((u >> 16) & 1u);
    unsigned h = r >> 16;
    *back = __uint_as_float(h << 16);
    return h;
}

// ---- split kernel: f32 -> 3x bf16 planes for x and W, + exact ssum --------
// one block per source row (4096 rows total: x then W); thread = one k-octet.
__global__ __launch_bounds__(256)
void split_kernel(const float* __restrict__ x, const float* __restrict__ W,
                  double* __restrict__ ssum) {
    const int row = blockIdx.x;
    const int tid = threadIdx.x;
    const int mat = row >> 11;          // 0 = x, 1 = W
    const int r   = row & 2047;
    const float* src = (mat ? W : x) + (size_t)r * N_DIM;
    unsigned short* p0 = g_planes + (size_t)(3 * mat) * PLANE
                       + (size_t)r * N_DIM + tid * 8;

    float4 f0 = *(const float4*)(src + tid * 8);
    float4 f1 = *(const float4*)(src + tid * 8 + 4);
    float v[8] = {f0.x, f0.y, f0.z, f0.w, f1.x, f1.y, f1.z, f1.w};
    unsigned h0[8], h1[8], h2[8];
    double s = 0.0;
#pragma unroll
    for (int e = 0; e < 8; ++e) {
        float b;
        h0[e] = bf16_rne(v[e], &b); float r1 = v[e] - b;   // exact residuals
        h1[e] = bf16_rne(r1, &b);   float r2 = r1 - b;
        h2[e] = bf16_rne(r2, &b);
        s += (double)v[e];
    }
    uint4 u;
    u.x = h0[0] | (h0[1] << 16); u.y = h0[2] | (h0[3] << 16);
    u.z = h0[4] | (h0[5] << 16); u.w = h0[6] | (h0[7] << 16);
    *(uint4*)(p0) = u;
    u.x = h1[0] | (h1[1] << 16); u.y = h1[2] | (h1[3] << 16);
    u.z = h1[4] | (h1[5] << 16); u.w = h1[6] | (h1[7] << 16);
    *(uint4*)(p0 + PLANE) = u;
    u.x = h2[0] | (h2[1] << 16); u.y = h2[2] | (h2[3] << 16);
    u.z = h2[4] | (h2[5] << 16); u.w = h2[6] | (h2[7] << 16);
    *(uint4*)(p0 + 2 * PLANE) = u;

    if (mat == 0) {   // spatial row sum (exact f64, fixed order)
        for (int off = 32; off > 0; off >>= 1) s += __shfl_down(s, off, 64);
        __shared__ double wsum[4];
        int lane = tid & 63, wv = tid >> 6;
        if (lane == 0) wsum[wv] = s;
        __syncthreads();
        if (tid == 0) ssum[r] = (wsum[0] + wsum[1]) + (wsum[2] + wsum[3]);
    }
}

// ---- bf16 MFMA wiring probe ------------------------------------------------
// Validates the documented 16x16x32 layout (A: row=l&15, k=8*(l>>4)+j; B
// symmetric) against 8 hypotheses: arg-swap x 4 D-forms. Asymmetric integer
// data -> only the true wiring matches (exact compare). Failure -> fallback.
__device__ unsigned probe_bf16(float* crefF, int l) {
    int i0 = l >> 2, j0 = (l & 3) << 2;
    for (int jj = 0; jj < 4; ++jj) {
        double s = 0.0;
        for (int k = 0; k < 32; ++k) s += probeA(i0, k) * probeB(k, j0 + jj);
        crefF[i0 * 16 + j0 + jj] = (float)s;      // <= 3872, exact in f32
    }
    __syncthreads();
    short8 af, bf;
#pragma unroll
    for (int j = 0; j < 8; ++j) {
        int k = 8 * (l >> 4) + j;
        af[j] = (short)(__float_as_uint((float)probeA(l & 15, k)) >> 16);
        bf[j] = (short)(__float_as_uint((float)probeB(k, l & 15)) >> 16);
    }
    unsigned win = 0xFFFFFFFFu;
    for (int s = 0; s < 2; ++s) {
        f32x4 d = {0.f, 0.f, 0.f, 0.f};
        d = __builtin_amdgcn_mfma_f32_16x16x32_bf16(s ? bf : af, s ? af : bf,
                                                    d, 0, 0, 0);
        for (int dF = 0; dF < 4; ++dF) {
            float err = 0.f;
#pragma unroll
            for (int r = 0; r < 4; ++r) {
                int ii, jj;
                if (dF == 0)      { ii = 4 * (l >> 4) + r; jj = l & 15; }
                else if (dF == 1) { ii = (l >> 4) + 4 * r; jj = l & 15; }
                else if (dF == 2) { jj = 4 * (l >> 4) + r; ii = l & 15; }
                else              { jj = (l >> 4) + 4 * r; ii = l & 15; }
                err = fmaxf(err, fabsf(d[r] - crefF[ii * 16 + jj]));
            }
            for (int off = 1; off < 64; off <<= 1)
                err = fmaxf(err, __shfl_xor(err, off, 64));
            if (err < 0.5f && win == 0xFFFFFFFFu) win = (unsigned)(s * 4 + dF);
        }
    }
    return win;
}

// ---- GEMM h = x . W^T via 3-way bf16 split (6 MFMA products) ---------------
// v21: R9's 4-wave k-split schedule (correctness-validated there) rerun with
// the two post-R9 changes that remove its failure mode:
//  - merged single acc[4][4] (64 AGPRs; absmax=0 validated in R10)
//  - __launch_bounds__(256,2): reg cap 256, compiler keeps its natural ~88
//    (R9's (256,3) cap ~170 vs the then-128-reg accumulator was the sole
//    cause of the 627MB scratch spill).
// R10 PMC: FETCH 194->76MB (swizzle works), MfmaUtil 20.6% at 2 waves/SIMD
// -> occupancy is grid-shape-bound, not register-bound. 4 waves/block at
// identical per-wave code -> 16 waves/CU = 4/SIMD, doubling latency cover.
#define MF(a, b, c) __builtin_amdgcn_mfma_f32_16x16x32_bf16((a), (b), (c), 0, 0, 0)

#define SIX_AB                                                        \
    acc[f][g] = MF(aa0, bb0[g], acc[f][g]);                           \
    acc[f][g] = MF(aa0, bb1[g], acc[f][g]);                           \
    acc[f][g] = MF(aa1, bb0[g], acc[f][g]);                           \
    acc[f][g] = MF(aa1, bb1[g], acc[f][g]);                           \
    acc[f][g] = MF(aa0, bb2[g], acc[f][g]);                           \
    acc[f][g] = MF(aa2, bb0[g], acc[f][g]);

#define SIX_BA                                                        \
    acc[f][g] = MF(bb0[g], aa0, acc[f][g]);                           \
    acc[f][g] = MF(bb1[g], aa0, acc[f][g]);                           \
    acc[f][g] = MF(bb0[g], aa1, acc[f][g]);                           \
    acc[f][g] = MF(bb1[g], aa1, acc[f][g]);                           \
    acc[f][g] = MF(bb2[g], aa0, acc[f][g]);                           \
    acc[f][g] = MF(bb0[g], aa2, acc[f][g]);

#define MAINLOOP(SIX)                                                 \
    for (int c = w; c < 64; c += 4) {                                 \
        const int koff = c * 32;                                      \
        short8 bb0[4], bb1[4], bb2[4];                                \
        _Pragma("unroll")                                             \
        for (int g = 0; g < 4; ++g) {                                 \
            const unsigned short* bp = Bbase + (size_t)(16 * g) * N_DIM + koff; \
            bb0[g] = *(const short8*)(bp);                            \
            bb1[g] = *(const short8*)(bp + PLANE);                    \
            bb2[g] = *(const short8*)(bp + 2 * PLANE);                \
        }                                                             \
        _Pragma("unroll")                                             \
        for (int f = 0; f < 4; ++f) {                                 \
            const unsigned short* ap = Abase + (size_t)(16 * f) * N_DIM + koff; \
            short8 aa0 = *(const short8*)(ap);                        \
            short8 aa1 = *(const short8*)(ap + PLANE);                \
            short8 aa2 = *(const short8*)(ap + 2 * PLANE);            \
            _Pragma("unroll")                                         \
            for (int g = 0; g < 4; ++g) { SIX }                       \
        }                                                             \
    }

// scatter-position loop over this wave's 64 accumulator elements
#define EPI(OP)                                                       \
    _Pragma("unroll")                                                 \
    for (int f = 0; f < 4; ++f)                                       \
        _Pragma("unroll")                                             \
        for (int g = 0; g < 4; ++g)                                   \
            _Pragma("unroll")                                         \
            for (int r = 0; r < 4; ++r) {                             \
                int ci = (16 * f + iD[r]) * 64 + 16 * g + jD[r];      \
                double sv = (double)acc[f][g][r];                     \
                OP;                                                   \
            }

__global__ __launch_bounds__(256, 2)
void gemm_bf16(const float* __restrict__ x, const float* __restrict__ W,
               float* __restrict__ C, double* __restrict__ psum,
               double* __restrict__ psum2) {
    __shared__ __align__(16) char smem[32768];   // probe Cref, then cbuf
    const int t    = threadIdx.x;
    const int lane = t & 63;
    const int w    = t >> 6;

    // XCD-aware slab swizzle: bid&7 = XCD; each XCD gets an 8x16 block slab.
    const int bid = blockIdx.y * 32 + blockIdx.x;
    const int xcd = bid & 7, ii = bid >> 3;
    const int bx = (xcd & 3) * 8 + (ii & 7);
    const int by = (xcd >> 2) * 16 + (ii >> 3);
    const int row0 = by * 64;
    const int col0 = bx * 64;
    const int band = by;

    const unsigned win = probe_bf16((float*)smem, lane);
    __syncthreads();
    double* cbuf = (double*)smem;                // 4096 doubles = 32KB

    if (win <= 7u) {
        const int swp = win >> 2, dF = win & 3;
        int iD[4], jD[4];
#pragma unroll
        for (int r = 0; r < 4; ++r) {
            if (dF == 0)      { iD[r] = 4 * (lane >> 4) + r; jD[r] = lane & 15; }
            else if (dF == 1) { iD[r] = (lane >> 4) + 4 * r; jD[r] = lane & 15; }
            else if (dF == 2) { jD[r] = 4 * (lane >> 4) + r; iD[r] = lane & 15; }
            else              { jD[r] = (lane >> 4) + 4 * r; iD[r] = lane & 15; }
        }

        const unsigned short* Abase =
            g_planes + (size_t)(row0 + (lane & 15)) * N_DIM + 8 * (lane >> 4);
        const unsigned short* Bbase =
            g_planes + 3 * PLANE + (size_t)(col0 + (lane & 15)) * N_DIM + 8 * (lane >> 4);

        f32x4 acc[4][4];
#pragma unroll
        for (int f = 0; f < 4; ++f)
#pragma unroll
            for (int g = 0; g < 4; ++g)
                acc[f][g] = (f32x4){0.f, 0.f, 0.f, 0.f};

        if (!swp) { MAINLOOP(SIX_AB) } else { MAINLOOP(SIX_BA) }

        // 4-wave combine: in-place accumulation at scatter position (all
        // waves share the identical lane->(i,j) map).
        __syncthreads();
        if (w == 1) { EPI(cbuf[ci] = sv) }
        __syncthreads();
        if (w == 2) { EPI(cbuf[ci] += sv) }
        __syncthreads();
        if (w == 3) { EPI(cbuf[ci] += sv) }
        __syncthreads();
        if (w == 0) {
            EPI(
                double vv = cbuf[ci] + sv;
                cbuf[ci] = vv;
                C[(size_t)(row0 + 16 * f + iD[r]) * N_DIM
                  + col0 + 16 * g + jD[r]] = (float)vv
            )
            // column stats over the 64x64 tile (same-wave DS ordering)
            double s = 0.0, q = 0.0;
#pragma unroll
            for (int r = 0; r < 64; ++r) {
                double v = cbuf[r * 64 + lane];
                s += v;
                q = fma(v, v, q);
            }
            psum [band * N_DIM + col0 + lane] = s;
            psum2[band * N_DIM + col0 + lane] = q;
        }
    } else {
        // correctness-only fallback (probe failed): naive f64 dot products
        for (int off = t; off < 64 * 64; off += 256) {
            int rr = off >> 6, cc = off & 63;
            const float* xr = x + (size_t)(row0 + rr) * N_DIM;
            const float* wr = W + (size_t)(col0 + cc) * N_DIM;
            double s = 0.0;
            for (int k = 0; k < N_DIM; ++k)
                s += (double)xr[k] * (double)wr[k];
            C[(size_t)(row0 + rr) * N_DIM + col0 + cc] = (float)s;
        }
        __syncthreads();
        if (t < 64) {
            double s = 0.0, q = 0.0;
            for (int rr = 0; rr < 64; ++rr) {
                double v = (double)C[(size_t)(row0 + rr) * N_DIM + col0 + t];
                s += v;
                q = fma(v, v, q);
            }
            psum [band * N_DIM + col0 + t] = s;
            psum2[band * N_DIM + col0 + t] = q;
        }
    }
}

// ---- fused BN-final + BN-apply + temporal-sum + triple LIF + output -------
__global__ __launch_bounds__(256)
void fused_lif_kernel(const float* __restrict__ x, const float* __restrict__ h,
                      const double* __restrict__ psum, const double* __restrict__ psum2,
                      const float* __restrict__ gamma, const float* __restrict__ beta,
                      const double* __restrict__ ssum, float* __restrict__ out) {
    int idx = blockIdx.x * 256 + threadIdx.x;
    int n = idx & (N_DIM - 1);
    int b = idx >> 11;
    // BN scale/shift for this column
    double s = 0.0, s2 = 0.0;
#pragma unroll
    for (int c = 0; c < 32; ++c) {
        s  += psum [c * N_DIM + n];
        s2 += psum2[c * N_DIM + n];
    }
    double mean = s * (1.0 / 2048.0);
    double var  = s2 * (1.0 / 2048.0) - mean * mean;
    double istd = 1.0 / sqrt(var + 1e-5);
    double sc = istd * (double)gamma[n];
    double sh = (double)beta[n] - mean * sc;
    // temporal sum (ascending t, f64)
    float xv[T_DIM];
    double ts = 0.0;
#pragma unroll
    for (int t = 0; t < T_DIM; ++t) {
        xv[t] = x[(size_t)(t * B_DIM + b) * N_DIM + n];
        ts += (double)xv[t];
    }
    double v1 = 0.0, v2 = 0.0, v3 = 0.0;
#pragma unroll
    for (int t = 0; t < T_DIM; ++t) {
        size_t off = (size_t)(t * B_DIM + b) * N_DIM + n;
        double hv = fma((double)h[off], sc, sh);
        v1 = v1 * 0.5 + hv;
        bool s1 = (v1 >= 1.0); if (s1) v1 = 0.0;
        double in2 = s1 ? ssum[t * B_DIM + b] : 0.0;
        v2 = v2 * 0.5 + in2;
        bool s2b = (v2 >= 1.0); if (s2b) v2 = 0.0;
        double in3 = s1 ? ts : 0.0;
        v3 = v3 * 0.5 + in3;
        bool s3 = (v3 >= 1.0); if (s3) v3 = 0.0;
        out[off] = xv[t] + ((s2b && s3) ? 1.0f : 0.0f);
    }
}

extern "C" void kernel_launch(void* const* d_in, const int* in_sizes, int n_in,
                              void* d_out, int out_size, void* d_ws, size_t ws_size,
                              hipStream_t stream) {
    const float* x     = (const float*)d_in[0];   // [16,128,2048]
    const float* W     = (const float*)d_in[1];   // [2048,2048]
    const float* gamma = (const float*)d_in[2];   // [2048]
    const float* beta  = (const float*)d_in[3];   // [2048]
    float* out = (float*)d_out;

    char* ws = (char*)d_ws;
    float*  h     = (float*)(ws + WS_H);
    double* psum  = (double*)(ws + WS_PSUM);
    double* psum2 = (double*)(ws + WS_PSUM2);
    double* ssum  = (double*)(ws + WS_SSUM);

    split_kernel<<<4096, 256, 0, stream>>>(x, W, ssum);
    gemm_bf16<<<dim3(32, 32), 256, 0, stream>>>(x, W, h, psum, psum2);
    fused_lif_kernel<<<(B_DIM * N_DIM) / 256, 256, 0, stream>>>(
        x, h, psum, psum2, gamma, beta, ssum, out);
}

// Round 12
// 296.000 us; speedup vs baseline: 1.1014x; 1.1014x over previous
//
#include <hip/hip_runtime.h>
#include <math.h>

// Problem constants
#define T_DIM 16
#define B_DIM 128
#define N_DIM 2048
#define TB    (T_DIM * B_DIM)   // 2048 rows of the GEMM

// d_ws layout (bytes): h f32 16MB | psum 0.5MB | psum2 0.5MB | ssum 16KB
#define WS_H      0
#define WS_PSUM   16777216
#define WS_PSUM2  17301504
#define WS_SSUM   17825792

typedef __attribute__((ext_vector_type(8))) short short8;
typedef __attribute__((ext_vector_type(4))) float f32x4;

// bf16 split planes: [x0,x1,x2,W0,W1,W2], each [2048][2048] bf16 = 8MB.
// Static device global (module-load allocation; not hipMalloc -> graph-safe).
#define PLANE 4194304ull
__device__ __align__(16) unsigned short g_planes[6ull * PLANE];

// ---- probe helpers (asymmetric integer patterns, exact in bf16/f32) -------
__device__ __forceinline__ double probeA(int m, int k) {
    return (double)((m * 7 + k * 13) % 23 - 11);
}
__device__ __forceinline__ double probeB(int k, int n) {
    return (double)((k * 5 + n * 3) % 19 - 9);
}

// round-to-nearest-even f32 -> bf16; returns bits, writes back-converted f32
__device__ __forceinline__ unsigned bf16_rne(float f, float* back) {
    unsigned u = __float_as_uint(f);
    unsigned r = u + 0x7FFFu + ((u >> 16) & 1u);
    unsigned h = r >> 16;
    *back = __uint_as_float(h << 16);
    return h;
}

// ---- split kernel: f32 -> 3x bf16 planes for x and W, + exact ssum --------
// one block per source row (4096 rows total: x then W); thread = one k-octet.
__global__ __launch_bounds__(256)
void split_kernel(const float* __restrict__ x, const float* __restrict__ W,
                  double* __restrict__ ssum) {
    const int row = blockIdx.x;
    const int tid = threadIdx.x;
    const int mat = row >> 11;          // 0 = x, 1 = W
    const int r   = row & 2047;
    const float* src = (mat ? W : x) + (size_t)r * N_DIM;
    unsigned short* p0 = g_planes + (size_t)(3 * mat) * PLANE
                       + (size_t)r * N_DIM + tid * 8;

    float4 f0 = *(const float4*)(src + tid * 8);
    float4 f1 = *(const float4*)(src + tid * 8 + 4);
    float v[8] = {f0.x, f0.y, f0.z, f0.w, f1.x, f1.y, f1.z, f1.w};
    unsigned h0[8], h1[8], h2[8];
    double s = 0.0;
#pragma unroll
    for (int e = 0; e < 8; ++e) {
        float b;
        h0[e] = bf16_rne(v[e], &b); float r1 = v[e] - b;   // exact residuals
        h1[e] = bf16_rne(r1, &b);   float r2 = r1 - b;
        h2[e] = bf16_rne(r2, &b);
        s += (double)v[e];
    }
    uint4 u;
    u.x = h0[0] | (h0[1] << 16); u.y = h0[2] | (h0[3] << 16);
    u.z = h0[4] | (h0[5] << 16); u.w = h0[6] | (h0[7] << 16);
    *(uint4*)(p0) = u;
    u.x = h1[0] | (h1[1] << 16); u.y = h1[2] | (h1[3] << 16);
    u.z = h1[4] | (h1[5] << 16); u.w = h1[6] | (h1[7] << 16);
    *(uint4*)(p0 + PLANE) = u;
    u.x = h2[0] | (h2[1] << 16); u.y = h2[2] | (h2[3] << 16);
    u.z = h2[4] | (h2[5] << 16); u.w = h2[6] | (h2[7] << 16);
    *(uint4*)(p0 + 2 * PLANE) = u;

    if (mat == 0) {   // spatial row sum (exact f64, fixed order)
        for (int off = 32; off > 0; off >>= 1) s += __shfl_down(s, off, 64);
        __shared__ double wsum[4];
        int lane = tid & 63, wv = tid >> 6;
        if (lane == 0) wsum[wv] = s;
        __syncthreads();
        if (tid == 0) ssum[r] = (wsum[0] + wsum[1]) + (wsum[2] + wsum[3]);
    }
}

// ---- bf16 MFMA wiring probe ------------------------------------------------
// Validates the documented 16x16x32 layout (A: row=l&15, k=8*(l>>4)+j; B
// symmetric) against 8 hypotheses: arg-swap x 4 D-forms. Asymmetric integer
// data -> only the true wiring matches (exact compare). Failure -> fallback.
__device__ unsigned probe_bf16(float* crefF, int l) {
    int i0 = l >> 2, j0 = (l & 3) << 2;
    for (int jj = 0; jj < 4; ++jj) {
        double s = 0.0;
        for (int k = 0; k < 32; ++k) s += probeA(i0, k) * probeB(k, j0 + jj);
        crefF[i0 * 16 + j0 + jj] = (float)s;      // <= 3872, exact in f32
    }
    __syncthreads();
    short8 af, bf;
#pragma unroll
    for (int j = 0; j < 8; ++j) {
        int k = 8 * (l >> 4) + j;
        af[j] = (short)(__float_as_uint((float)probeA(l & 15, k)) >> 16);
        bf[j] = (short)(__float_as_uint((float)probeB(k, l & 15)) >> 16);
    }
    unsigned win = 0xFFFFFFFFu;
    for (int s = 0; s < 2; ++s) {
        f32x4 d = {0.f, 0.f, 0.f, 0.f};
        d = __builtin_amdgcn_mfma_f32_16x16x32_bf16(s ? bf : af, s ? af : bf,
                                                    d, 0, 0, 0);
        for (int dF = 0; dF < 4; ++dF) {
            float err = 0.f;
#pragma unroll
            for (int r = 0; r < 4; ++r) {
                int ii, jj;
                if (dF == 0)      { ii = 4 * (l >> 4) + r; jj = l & 15; }
                else if (dF == 1) { ii = (l >> 4) + 4 * r; jj = l & 15; }
                else if (dF == 2) { jj = 4 * (l >> 4) + r; ii = l & 15; }
                else              { jj = (l >> 4) + 4 * r; ii = l & 15; }
                err = fmaxf(err, fabsf(d[r] - crefF[ii * 16 + jj]));
            }
            for (int off = 1; off < 64; off <<= 1)
                err = fmaxf(err, __shfl_xor(err, off, 64));
            if (err < 0.5f && win == 0xFFFFFFFFu) win = (unsigned)(s * 4 + dF);
        }
    }
    return win;
}

// ---- GEMM h = x . W^T via 3-way bf16 split (6 MFMA products) ---------------
// v22: R10 shell (128 thr, 2-wave k-split, grid 32x32, launch_bounds(128,2),
// merged acc, XCD slab swizzle -- 208us proven) with ONE change: batched
// chunk loads. R10/R11 arithmetic: per chunk 96 MFMAs = 466cy but wall =
// ~13600cy = 24 loads x ~540cy SERIALIZED -- the old loop loaded A inside
// the f-loop with MFMAs consuming immediately (~5 dependent L2 round trips
// per chunk). Now ALL 24 loads (12 B + 12 A = 96 VGPRs) issue before any
// MFMA: 1 round trip per chunk. Budget: 96 live + 64 acc + ~20 addr = 180
// < 256 cap -> no spill (R3/R5/R9 rule). R11's 4-wave variant reverted
// (occupancy stuck at 22% regardless; barriers+L2 contention cost 13%).
#define MF(a, b, c) __builtin_amdgcn_mfma_f32_16x16x32_bf16((a), (b), (c), 0, 0, 0)

#define SIX_AB                                                        \
    acc[f][g] = MF(aa0[f], bb0[g], acc[f][g]);                        \
    acc[f][g] = MF(aa0[f], bb1[g], acc[f][g]);                        \
    acc[f][g] = MF(aa1[f], bb0[g], acc[f][g]);                        \
    acc[f][g] = MF(aa1[f], bb1[g], acc[f][g]);                        \
    acc[f][g] = MF(aa0[f], bb2[g], acc[f][g]);                        \
    acc[f][g] = MF(aa2[f], bb0[g], acc[f][g]);

#define SIX_BA                                                        \
    acc[f][g] = MF(bb0[g], aa0[f], acc[f][g]);                        \
    acc[f][g] = MF(bb1[g], aa0[f], acc[f][g]);                        \
    acc[f][g] = MF(bb0[g], aa1[f], acc[f][g]);                        \
    acc[f][g] = MF(bb1[g], aa1[f], acc[f][g]);                        \
    acc[f][g] = MF(bb2[g], aa0[f], acc[f][g]);                        \
    acc[f][g] = MF(bb0[g], aa2[f], acc[f][g]);

#define MAINLOOP(SIX)                                                 \
    for (int c = w; c < 64; c += 2) {                                 \
        const int koff = c * 32;                                      \
        short8 bb0[4], bb1[4], bb2[4];                                \
        short8 aa0[4], aa1[4], aa2[4];                                \
        _Pragma("unroll")                                             \
        for (int g = 0; g < 4; ++g) {                                 \
            const unsigned short* bp = Bbase + (size_t)(16 * g) * N_DIM + koff; \
            bb0[g] = *(const short8*)(bp);                            \
            bb1[g] = *(const short8*)(bp + PLANE);                    \
            bb2[g] = *(const short8*)(bp + 2 * PLANE);                \
        }                                                             \
        _Pragma("unroll")                                             \
        for (int f = 0; f < 4; ++f) {                                 \
            const unsigned short* ap = Abase + (size_t)(16 * f) * N_DIM + koff; \
            aa0[f] = *(const short8*)(ap);                            \
            aa1[f] = *(const short8*)(ap + PLANE);                    \
            aa2[f] = *(const short8*)(ap + 2 * PLANE);                \
        }                                                             \
        _Pragma("unroll")                                             \
        for (int f = 0; f < 4; ++f)                                   \
            _Pragma("unroll")                                         \
            for (int g = 0; g < 4; ++g) { SIX }                       \
    }

// scatter-position loop over this wave's 64 accumulator elements
#define EPI(OP)                                                       \
    _Pragma("unroll")                                                 \
    for (int f = 0; f < 4; ++f)                                       \
        _Pragma("unroll")                                             \
        for (int g = 0; g < 4; ++g)                                   \
            _Pragma("unroll")                                         \
            for (int r = 0; r < 4; ++r) {                             \
                int ci = (16 * f + iD[r]) * 64 + 16 * g + jD[r];      \
                double sv = (double)acc[f][g][r];                     \
                OP;                                                   \
            }

__global__ __launch_bounds__(128, 2)
void gemm_bf16(const float* __restrict__ x, const float* __restrict__ W,
               float* __restrict__ C, double* __restrict__ psum,
               double* __restrict__ psum2) {
    __shared__ __align__(16) char smem[32768];   // probe Cref, then cbuf
    const int t    = threadIdx.x;
    const int lane = t & 63;
    const int w    = t >> 6;

    // XCD-aware slab swizzle: bid&7 = XCD; each XCD gets an 8x16 block slab.
    const int bid = blockIdx.y * 32 + blockIdx.x;
    const int xcd = bid & 7, ii = bid >> 3;
    const int bx = (xcd & 3) * 8 + (ii & 7);
    const int by = (xcd >> 2) * 16 + (ii >> 3);
    const int row0 = by * 64;
    const int col0 = bx * 64;
    const int band = by;

    const unsigned win = probe_bf16((float*)smem, lane);
    __syncthreads();
    double* cbuf = (double*)smem;                // 4096 doubles = 32KB

    if (win <= 7u) {
        const int swp = win >> 2, dF = win & 3;
        int iD[4], jD[4];
#pragma unroll
        for (int r = 0; r < 4; ++r) {
            if (dF == 0)      { iD[r] = 4 * (lane >> 4) + r; jD[r] = lane & 15; }
            else if (dF == 1) { iD[r] = (lane >> 4) + 4 * r; jD[r] = lane & 15; }
            else if (dF == 2) { jD[r] = 4 * (lane >> 4) + r; iD[r] = lane & 15; }
            else              { jD[r] = (lane >> 4) + 4 * r; iD[r] = lane & 15; }
        }

        const unsigned short* Abase =
            g_planes + (size_t)(row0 + (lane & 15)) * N_DIM + 8 * (lane >> 4);
        const unsigned short* Bbase =
            g_planes + 3 * PLANE + (size_t)(col0 + (lane & 15)) * N_DIM + 8 * (lane >> 4);

        f32x4 acc[4][4];
#pragma unroll
        for (int f = 0; f < 4; ++f)
#pragma unroll
            for (int g = 0; g < 4; ++g)
                acc[f][g] = (f32x4){0.f, 0.f, 0.f, 0.f};

        if (!swp) { MAINLOOP(SIX_AB) } else { MAINLOOP(SIX_BA) }

        // 2-wave combine: in-place accumulation at scatter position (both
        // waves share the identical lane->(i,j) map).
        __syncthreads();
        if (w == 1) { EPI(cbuf[ci] = sv) }
        __syncthreads();
        if (w == 0) {
            EPI(
                double vv = cbuf[ci] + sv;
                cbuf[ci] = vv;
                C[(size_t)(row0 + 16 * f + iD[r]) * N_DIM
                  + col0 + 16 * g + jD[r]] = (float)vv
            )
            // column stats over the 64x64 tile (same-wave DS ordering)
            double s = 0.0, q = 0.0;
#pragma unroll
            for (int r = 0; r < 64; ++r) {
                double v = cbuf[r * 64 + lane];
                s += v;
                q = fma(v, v, q);
            }
            psum [band * N_DIM + col0 + lane] = s;
            psum2[band * N_DIM + col0 + lane] = q;
        }
    } else {
        // correctness-only fallback (probe failed): naive f64 dot products
        for (int off = t; off < 64 * 64; off += 128) {
            int rr = off >> 6, cc = off & 63;
            const float* xr = x + (size_t)(row0 + rr) * N_DIM;
            const float* wr = W + (size_t)(col0 + cc) * N_DIM;
            double s = 0.0;
            for (int k = 0; k < N_DIM; ++k)
                s += (double)xr[k] * (double)wr[k];
            C[(size_t)(row0 + rr) * N_DIM + col0 + cc] = (float)s;
        }
        __syncthreads();
        if (t < 64) {
            double s = 0.0, q = 0.0;
            for (int rr = 0; rr < 64; ++rr) {
                double v = (double)C[(size_t)(row0 + rr) * N_DIM + col0 + t];
                s += v;
                q = fma(v, v, q);
            }
            psum [band * N_DIM + col0 + t] = s;
            psum2[band * N_DIM + col0 + t] = q;
        }
    }
}

// ---- fused BN-final + BN-apply + temporal-sum + triple LIF + output -------
__global__ __launch_bounds__(256)
void fused_lif_kernel(const float* __restrict__ x, const float* __restrict__ h,
                      const double* __restrict__ psum, const double* __restrict__ psum2,
                      const float* __restrict__ gamma, const float* __restrict__ beta,
                      const double* __restrict__ ssum, float* __restrict__ out) {
    int idx = blockIdx.x * 256 + threadIdx.x;
    int n = idx & (N_DIM - 1);
    int b = idx >> 11;
    // BN scale/shift for this column
    double s = 0.0, s2 = 0.0;
#pragma unroll
    for (int c = 0; c < 32; ++c) {
        s  += psum [c * N_DIM + n];
        s2 += psum2[c * N_DIM + n];
    }
    double mean = s * (1.0 / 2048.0);
    double var  = s2 * (1.0 / 2048.0) - mean * mean;
    double istd = 1.0 / sqrt(var + 1e-5);
    double sc = istd * (double)gamma[n];
    double sh = (double)beta[n] - mean * sc;
    // temporal sum (ascending t, f64)
    float xv[T_DIM];
    double ts = 0.0;
#pragma unroll
    for (int t = 0; t < T_DIM; ++t) {
        xv[t] = x[(size_t)(t * B_DIM + b) * N_DIM + n];
        ts += (double)xv[t];
    }
    double v1 = 0.0, v2 = 0.0, v3 = 0.0;
#pragma unroll
    for (int t = 0; t < T_DIM; ++t) {
        size_t off = (size_t)(t * B_DIM + b) * N_DIM + n;
        double hv = fma((double)h[off], sc, sh);
        v1 = v1 * 0.5 + hv;
        bool s1 = (v1 >= 1.0); if (s1) v1 = 0.0;
        double in2 = s1 ? ssum[t * B_DIM + b] : 0.0;
        v2 = v2 * 0.5 + in2;
        bool s2b = (v2 >= 1.0); if (s2b) v2 = 0.0;
        double in3 = s1 ? ts : 0.0;
        v3 = v3 * 0.5 + in3;
        bool s3 = (v3 >= 1.0); if (s3) v3 = 0.0;
        out[off] = xv[t] + ((s2b && s3) ? 1.0f : 0.0f);
    }
}

extern "C" void kernel_launch(void* const* d_in, const int* in_sizes, int n_in,
                              void* d_out, int out_size, void* d_ws, size_t ws_size,
                              hipStream_t stream) {
    const float* x     = (const float*)d_in[0];   // [16,128,2048]
    const float* W     = (const float*)d_in[1];   // [2048,2048]
    const float* gamma = (const float*)d_in[2];   // [2048]
    const float* beta  = (const float*)d_in[3];   // [2048]
    float* out = (float*)d_out;

    char* ws = (char*)d_ws;
    float*  h     = (float*)(ws + WS_H);
    double* psum  = (double*)(ws + WS_PSUM);
    double* psum2 = (double*)(ws + WS_PSUM2);
    double* ssum  = (double*)(ws + WS_SSUM);

    split_kernel<<<4096, 256, 0, stream>>>(x, W, ssum);
    gemm_bf16<<<dim3(32, 32), 128, 0, stream>>>(x, W, h, psum, psum2);
    fused_lif_kernel<<<(B_DIM * N_DIM) / 256, 256, 0, stream>>>(
        x, h, psum, psum2, gamma, beta, ssum, out);
}

// Round 13
// 274.900 us; speedup vs baseline: 1.1859x; 1.0768x over previous
//
#include <hip/hip_runtime.h>
#include <math.h>

// Problem constants
#define T_DIM 16
#define B_DIM 128
#define N_DIM 2048
#define TB    (T_DIM * B_DIM)   // 2048 rows of the GEMM

// d_ws layout (bytes): h f32 16MB | psum 0.5MB | psum2 0.5MB | ssum 16KB
#define WS_H      0
#define WS_PSUM   16777216
#define WS_PSUM2  17301504
#define WS_SSUM   17825792

typedef __attribute__((ext_vector_type(8))) short short8;
typedef __attribute__((ext_vector_type(4))) float f32x4;

// bf16 split planes: [x0,x1,x2,W0,W1,W2], each [2048][2048] bf16 = 8MB.
// Static device global (module-load allocation; not hipMalloc -> graph-safe).
#define PLANE 4194304ull
__device__ __align__(16) unsigned short g_planes[6ull * PLANE];

// ---- probe helpers (asymmetric integer patterns, exact in bf16/f32) -------
__device__ __forceinline__ double probeA(int m, int k) {
    return (double)((m * 7 + k * 13) % 23 - 11);
}
__device__ __forceinline__ double probeB(int k, int n) {
    return (double)((k * 5 + n * 3) % 19 - 9);
}

// round-to-nearest-even f32 -> bf16; returns bits, writes back-converted f32
__device__ __forceinline__ unsigned bf16_rne(float f, float* back) {
    unsigned u = __float_as_uint(f);
    unsigned r = u + 0x7FFFu + ((u >> 16) & 1u);
    unsigned h = r >> 16;
    *back = __uint_as_float(h << 16);
    return h;
}

// async global->LDS, 16B per lane: LDS dest = wave-uniform base + lane*16.
__device__ __forceinline__ void gload16(const unsigned short* g, char* l) {
    __builtin_amdgcn_global_load_lds(
        (const __attribute__((address_space(1))) void*)g,
        (__attribute__((address_space(3))) void*)l, 16, 0, 0);
}

// ---- split kernel: f32 -> 3x bf16 planes for x and W, + exact ssum --------
// one block per source row (4096 rows total: x then W); thread = one k-octet.
__global__ __launch_bounds__(256)
void split_kernel(const float* __restrict__ x, const float* __restrict__ W,
                  double* __restrict__ ssum) {
    const int row = blockIdx.x;
    const int tid = threadIdx.x;
    const int mat = row >> 11;          // 0 = x, 1 = W
    const int r   = row & 2047;
    const float* src = (mat ? W : x) + (size_t)r * N_DIM;
    unsigned short* p0 = g_planes + (size_t)(3 * mat) * PLANE
                       + (size_t)r * N_DIM + tid * 8;

    float4 f0 = *(const float4*)(src + tid * 8);
    float4 f1 = *(const float4*)(src + tid * 8 + 4);
    float v[8] = {f0.x, f0.y, f0.z, f0.w, f1.x, f1.y, f1.z, f1.w};
    unsigned h0[8], h1[8], h2[8];
    double s = 0.0;
#pragma unroll
    for (int e = 0; e < 8; ++e) {
        float b;
        h0[e] = bf16_rne(v[e], &b); float r1 = v[e] - b;   // exact residuals
        h1[e] = bf16_rne(r1, &b);   float r2 = r1 - b;
        h2[e] = bf16_rne(r2, &b);
        s += (double)v[e];
    }
    uint4 u;
    u.x = h0[0] | (h0[1] << 16); u.y = h0[2] | (h0[3] << 16);
    u.z = h0[4] | (h0[5] << 16); u.w = h0[6] | (h0[7] << 16);
    *(uint4*)(p0) = u;
    u.x = h1[0] | (h1[1] << 16); u.y = h1[2] | (h1[3] << 16);
    u.z = h1[4] | (h1[5] << 16); u.w = h1[6] | (h1[7] << 16);
    *(uint4*)(p0 + PLANE) = u;
    u.x = h2[0] | (h2[1] << 16); u.y = h2[2] | (h2[3] << 16);
    u.z = h2[4] | (h2[5] << 16); u.w = h2[6] | (h2[7] << 16);
    *(uint4*)(p0 + 2 * PLANE) = u;

    if (mat == 0) {   // spatial row sum (exact f64, fixed order)
        for (int off = 32; off > 0; off >>= 1) s += __shfl_down(s, off, 64);
        __shared__ double wsum[4];
        int lane = tid & 63, wv = tid >> 6;
        if (lane == 0) wsum[wv] = s;
        __syncthreads();
        if (tid == 0) ssum[r] = (wsum[0] + wsum[1]) + (wsum[2] + wsum[3]);
    }
}

// ---- bf16 MFMA wiring probe ------------------------------------------------
__device__ unsigned probe_bf16(float* crefF, int l) {
    int i0 = l >> 2, j0 = (l & 3) << 2;
    for (int jj = 0; jj < 4; ++jj) {
        double s = 0.0;
        for (int k = 0; k < 32; ++k) s += probeA(i0, k) * probeB(k, j0 + jj);
        crefF[i0 * 16 + j0 + jj] = (float)s;      // <= 3872, exact in f32
    }
    __syncthreads();
    short8 af, bf;
#pragma unroll
    for (int j = 0; j < 8; ++j) {
        int k = 8 * (l >> 4) + j;
        af[j] = (short)(__float_as_uint((float)probeA(l & 15, k)) >> 16);
        bf[j] = (short)(__float_as_uint((float)probeB(k, l & 15)) >> 16);
    }
    unsigned win = 0xFFFFFFFFu;
    for (int s = 0; s < 2; ++s) {
        f32x4 d = {0.f, 0.f, 0.f, 0.f};
        d = __builtin_amdgcn_mfma_f32_16x16x32_bf16(s ? bf : af, s ? af : bf,
                                                    d, 0, 0, 0);
        for (int dF = 0; dF < 4; ++dF) {
            float err = 0.f;
#pragma unroll
            for (int r = 0; r < 4; ++r) {
                int ii, jj;
                if (dF == 0)      { ii = 4 * (l >> 4) + r; jj = l & 15; }
                else if (dF == 1) { ii = (l >> 4) + 4 * r; jj = l & 15; }
                else if (dF == 2) { jj = 4 * (l >> 4) + r; ii = l & 15; }
                else              { jj = (l >> 4) + 4 * r; ii = l & 15; }
                err = fmaxf(err, fabsf(d[r] - crefF[ii * 16 + jj]));
            }
            for (int off = 1; off < 64; off <<= 1)
                err = fmaxf(err, __shfl_xor(err, off, 64));
            if (err < 0.5f && win == 0xFFFFFFFFu) win = (unsigned)(s * 4 + dF);
        }
    }
    return win;
}

// ---- GEMM h = x . W^T via 3-way bf16 split (6 MFMA products) ---------------
// v23: LDS-staged dataflow. R12's VGPR_Count=92 proved register-batched
// loads are impossible (24 live short8 = 96 regs > what RA gives) -- loads
// serialize at ~600cy L3 latency. Fix per guide: global_load_lds staging
// (loads land in LDS, not VGPRs -> latency decoupled from liveness),
// double-buffered K=32 steps; prefetch of step t+1 overlaps compute of t.
//  - 4 waves; wave (wr,wc) owns a 32x32 quadrant: acc = 16 VGPRs, NO
//    cross-wave combine epilogue.
//  - per step per block: 24 gload16 (6/wave, 1KB each) stage A/B x 3 planes;
//    per wave 12 ds_read_b128 (bank-checked: 8 lanes/4-bank group = minimum
//    8 phases, conflict-free) + 24 MFMAs.
//  - floors: LDS-BW ~45us, MFMA ~41us; latency off the critical path.
#define MF(a, b, c) __builtin_amdgcn_mfma_f32_16x16x32_bf16((a), (b), (c), 0, 0, 0)
#define NSTEP 64
#define BUFB  24576    // bytes per LDS buffer: [A 3x4KB][B 3x4KB]

#define SIX_AB                                                        \
    acc[f][g] = MF(av[0][f], bv[0][g], acc[f][g]);                    \
    acc[f][g] = MF(av[0][f], bv[1][g], acc[f][g]);                    \
    acc[f][g] = MF(av[1][f], bv[0][g], acc[f][g]);                    \
    acc[f][g] = MF(av[1][f], bv[1][g], acc[f][g]);                    \
    acc[f][g] = MF(av[0][f], bv[2][g], acc[f][g]);                    \
    acc[f][g] = MF(av[2][f], bv[0][g], acc[f][g]);

#define SIX_BA                                                        \
    acc[f][g] = MF(bv[0][g], av[0][f], acc[f][g]);                    \
    acc[f][g] = MF(bv[1][g], av[0][f], acc[f][g]);                    \
    acc[f][g] = MF(bv[0][g], av[1][f], acc[f][g]);                    \
    acc[f][g] = MF(bv[1][g], av[1][f], acc[f][g]);                    \
    acc[f][g] = MF(bv[2][g], av[0][f], acc[f][g]);                    \
    acc[f][g] = MF(bv[0][g], av[2][f], acc[f][g]);

#define KLOOP(SIX)                                                    \
    for (int st = 0; st < NSTEP; ++st) {                              \
        const int cb = (st & 1) * BUFB;                               \
        if (st + 1 < NSTEP) {                                         \
            const int nb = ((st + 1) & 1) * BUFB;                     \
            _Pragma("unroll")                                         \
            for (int ii = 0; ii < 6; ++ii)                            \
                gload16(gsrc[ii] + (st + 1) * 32, smem + nb + ldso[ii]); \
        }                                                             \
        short8 av[3][2], bv[3][2];                                    \
        _Pragma("unroll")                                             \
        for (int p = 0; p < 3; ++p)                                   \
            _Pragma("unroll")                                         \
            for (int f = 0; f < 2; ++f) {                             \
                av[p][f] = *(const short8*)(smem + cb + p * 4096 + f * 1024 + aoffL); \
                bv[p][f] = *(const short8*)(smem + cb + p * 4096 + f * 1024 + boffL); \
            }                                                         \
        _Pragma("unroll")                                             \
        for (int f = 0; f < 2; ++f)                                   \
            _Pragma("unroll")                                         \
            for (int g = 0; g < 2; ++g) { SIX }                       \
        __syncthreads();                                              \
    }

__global__ __launch_bounds__(256, 2)
void gemm_bf16(const float* __restrict__ x, const float* __restrict__ W,
               float* __restrict__ C, double* __restrict__ psum,
               double* __restrict__ psum2) {
    __shared__ __align__(16) char smem[49152];   // 2 x 24KB staging; epi reuse
    const int t    = threadIdx.x;
    const int lane = t & 63;
    const int w    = t >> 6;
    const int wr   = w >> 1, wc = w & 1;

    // XCD-aware slab swizzle: bid&7 = XCD; each XCD gets an 8x16 block slab.
    const int bid = blockIdx.y * 32 + blockIdx.x;
    const int xcd = bid & 7, ii0 = bid >> 3;
    const int bx = (xcd & 3) * 8 + (ii0 & 7);
    const int by = (xcd >> 2) * 16 + (ii0 >> 3);
    const int row0 = by * 64;
    const int col0 = bx * 64;
    const int band = by;

    const unsigned win = probe_bf16((float*)smem, lane);
    __syncthreads();

    if (win <= 7u) {
        const int swp = win >> 2, dF = win & 3;
        int iD[4], jD[4];
#pragma unroll
        for (int r = 0; r < 4; ++r) {
            if (dF == 0)      { iD[r] = 4 * (lane >> 4) + r; jD[r] = lane & 15; }
            else if (dF == 1) { iD[r] = (lane >> 4) + 4 * r; jD[r] = lane & 15; }
            else if (dF == 2) { jD[r] = 4 * (lane >> 4) + r; iD[r] = lane & 15; }
            else              { jD[r] = (lane >> 4) + 4 * r; iD[r] = lane & 15; }
        }

        // staging descriptors: instr i = w + 4*ii; i<12 = A, else B.
        // each instr stages 1KB = 16 rows x 64B of one plane's K-slice.
        const unsigned short* gsrc[6];
        int ldso[6];
#pragma unroll
        for (int ii = 0; ii < 6; ++ii) {
            int i   = w + ii * 4;
            int m   = (i >= 12) ? 1 : 0;
            int r12 = i - 12 * m;
            int p   = r12 >> 2, qq = r12 & 3;
            int grow = (m ? col0 : row0) + qq * 16 + (lane >> 2);
            gsrc[ii] = g_planes + (size_t)(3 * m + p) * PLANE
                     + (size_t)grow * N_DIM + (lane & 3) * 8;
            ldso[ii] = m * 12288 + p * 4096 + qq * 1024;
        }

        // fragment read offsets (linear layout, conflict-free: words 16r+4q)
        const int aoffL = (32 * wr + (lane & 15)) * 64 + (lane >> 4) * 16;
        const int boffL = 12288 + (32 * wc + (lane & 15)) * 64 + (lane >> 4) * 16;

        f32x4 acc[2][2];
#pragma unroll
        for (int f = 0; f < 2; ++f)
#pragma unroll
            for (int g = 0; g < 2; ++g)
                acc[f][g] = (f32x4){0.f, 0.f, 0.f, 0.f};

        // stage step 0 -> buf0
#pragma unroll
        for (int ii = 0; ii < 6; ++ii)
            gload16(gsrc[ii], smem + ldso[ii]);
        __syncthreads();

        if (!swp) { KLOOP(SIX_AB) } else { KLOOP(SIX_BA) }

        // epilogue: direct C store + wave-private BN scatter (layout-agnostic)
        double* region = (double*)(smem + w * 8192);   // 32x32 doubles
#pragma unroll
        for (int f = 0; f < 2; ++f)
#pragma unroll
            for (int g = 0; g < 2; ++g)
#pragma unroll
                for (int r = 0; r < 4; ++r) {
                    region[(16 * f + iD[r]) * 32 + 16 * g + jD[r]] =
                        (double)acc[f][g][r];
                    C[(size_t)(row0 + 32 * wr + 16 * f + iD[r]) * N_DIM
                      + col0 + 32 * wc + 16 * g + jD[r]] = (float)acc[f][g][r];
                }
        // per-wave column partials (same-wave DS ordering; no barrier)
        {
            const int c = lane & 31, half = lane >> 5;
            double s = 0.0, q = 0.0;
#pragma unroll
            for (int r = 0; r < 16; ++r) {
                double v = region[(16 * half + r) * 32 + c];
                s += v;
                q = fma(v, v, q);
            }
            s += __shfl_xor(s, 32, 64);
            q += __shfl_xor(q, 32, 64);
            double* pbuf = (double*)(smem + 32768);    // [4][2][32]
            if (lane < 32) {
                pbuf[(w * 2 + 0) * 32 + c] = s;
                pbuf[(w * 2 + 1) * 32 + c] = q;
            }
        }
        __syncthreads();
        if (t < 64) {
            const int c2 = t & 31, wcc = t >> 5;
            double* pbuf = (double*)(smem + 32768);
            double s = pbuf[(wcc * 2 + 0) * 32 + c2]
                     + pbuf[((wcc + 2) * 2 + 0) * 32 + c2];
            double q = pbuf[(wcc * 2 + 1) * 32 + c2]
                     + pbuf[((wcc + 2) * 2 + 1) * 32 + c2];
            psum [band * N_DIM + col0 + 32 * wcc + c2] = s;
            psum2[band * N_DIM + col0 + 32 * wcc + c2] = q;
        }
    } else {
        // correctness-only fallback (probe failed): naive f64 dot products
        for (int off = t; off < 64 * 64; off += 256) {
            int rr = off >> 6, cc = off & 63;
            const float* xr = x + (size_t)(row0 + rr) * N_DIM;
            const float* wr2 = W + (size_t)(col0 + cc) * N_DIM;
            double s = 0.0;
            for (int k = 0; k < N_DIM; ++k)
                s += (double)xr[k] * (double)wr2[k];
            C[(size_t)(row0 + rr) * N_DIM + col0 + cc] = (float)s;
        }
        __syncthreads();
        if (t < 64) {
            double s = 0.0, q = 0.0;
            for (int rr = 0; rr < 64; ++rr) {
                double v = (double)C[(size_t)(row0 + rr) * N_DIM + col0 + t];
                s += v;
                q = fma(v, v, q);
            }
            psum [band * N_DIM + col0 + t] = s;
            psum2[band * N_DIM + col0 + t] = q;
        }
    }
}

// ---- fused BN-final + BN-apply + temporal-sum + triple LIF + output -------
__global__ __launch_bounds__(256)
void fused_lif_kernel(const float* __restrict__ x, const float* __restrict__ h,
                      const double* __restrict__ psum, const double* __restrict__ psum2,
                      const float* __restrict__ gamma, const float* __restrict__ beta,
                      const double* __restrict__ ssum, float* __restrict__ out) {
    int idx = blockIdx.x * 256 + threadIdx.x;
    int n = idx & (N_DIM - 1);
    int b = idx >> 11;
    // BN scale/shift for this column
    double s = 0.0, s2 = 0.0;
#pragma unroll
    for (int c = 0; c < 32; ++c) {
        s  += psum [c * N_DIM + n];
        s2 += psum2[c * N_DIM + n];
    }
    double mean = s * (1.0 / 2048.0);
    double var  = s2 * (1.0 / 2048.0) - mean * mean;
    double istd = 1.0 / sqrt(var + 1e-5);
    double sc = istd * (double)gamma[n];
    double sh = (double)beta[n] - mean * sc;
    // temporal sum (ascending t, f64)
    float xv[T_DIM];
    double ts = 0.0;
#pragma unroll
    for (int t = 0; t < T_DIM; ++t) {
        xv[t] = x[(size_t)(t * B_DIM + b) * N_DIM + n];
        ts += (double)xv[t];
    }
    double v1 = 0.0, v2 = 0.0, v3 = 0.0;
#pragma unroll
    for (int t = 0; t < T_DIM; ++t) {
        size_t off = (size_t)(t * B_DIM + b) * N_DIM + n;
        double hv = fma((double)h[off], sc, sh);
        v1 = v1 * 0.5 + hv;
        bool s1 = (v1 >= 1.0); if (s1) v1 = 0.0;
        double in2 = s1 ? ssum[t * B_DIM + b] : 0.0;
        v2 = v2 * 0.5 + in2;
        bool s2b = (v2 >= 1.0); if (s2b) v2 = 0.0;
        double in3 = s1 ? ts : 0.0;
        v3 = v3 * 0.5 + in3;
        bool s3 = (v3 >= 1.0); if (s3) v3 = 0.0;
        out[off] = xv[t] + ((s2b && s3) ? 1.0f : 0.0f);
    }
}

extern "C" void kernel_launch(void* const* d_in, const int* in_sizes, int n_in,
                              void* d_out, int out_size, void* d_ws, size_t ws_size,
                              hipStream_t stream) {
    const float* x     = (const float*)d_in[0];   // [16,128,2048]
    const float* W     = (const float*)d_in[1];   // [2048,2048]
    const float* gamma = (const float*)d_in[2];   // [2048]
    const float* beta  = (const float*)d_in[3];   // [2048]
    float* out = (float*)d_out;

    char* ws = (char*)d_ws;
    float*  h     = (float*)(ws + WS_H);
    double* psum  = (double*)(ws + WS_PSUM);
    double* psum2 = (double*)(ws + WS_PSUM2);
    double* ssum  = (double*)(ws + WS_SSUM);

    split_kernel<<<4096, 256, 0, stream>>>(x, W, ssum);
    gemm_bf16<<<dim3(32, 32), 256, 0, stream>>>(x, W, h, psum, psum2);
    fused_lif_kernel<<<(B_DIM * N_DIM) / 256, 256, 0, stream>>>(
        x, h, psum, psum2, gamma, beta, ssum, out);
}

// Round 14
// 273.112 us; speedup vs baseline: 1.1937x; 1.0065x over previous
//
#include <hip/hip_runtime.h>
#include <math.h>

// Problem constants
#define T_DIM 16
#define B_DIM 128
#define N_DIM 2048
#define TB    (T_DIM * B_DIM)   // 2048 rows of the GEMM

// d_ws layout (bytes): h f32 16MB | psum 0.5MB | psum2 0.5MB | ssum 16KB
#define WS_H      0
#define WS_PSUM   16777216
#define WS_PSUM2  17301504
#define WS_SSUM   17825792

typedef __attribute__((ext_vector_type(8))) short short8;
typedef __attribute__((ext_vector_type(4))) float f32x4;

// bf16 split planes: [x0,x1,x2,W0,W1,W2], each [2048][2048] bf16 = 8MB.
// Static device global (module-load allocation; not hipMalloc -> graph-safe).
#define PLANE 4194304ull
__device__ __align__(16) unsigned short g_planes[6ull * PLANE];

// ---- probe helpers (asymmetric integer patterns, exact in bf16/f32) -------
__device__ __forceinline__ double probeA(int m, int k) {
    return (double)((m * 7 + k * 13) % 23 - 11);
}
__device__ __forceinline__ double probeB(int k, int n) {
    return (double)((k * 5 + n * 3) % 19 - 9);
}

// round-to-nearest-even f32 -> bf16; returns bits, writes back-converted f32
__device__ __forceinline__ unsigned bf16_rne(float f, float* back) {
    unsigned u = __float_as_uint(f);
    unsigned r = u + 0x7FFFu + ((u >> 16) & 1u);
    unsigned h = r >> 16;
    *back = __uint_as_float(h << 16);
    return h;
}

// async global->LDS, 16B per lane: LDS dest = wave-uniform base + lane*16.
__device__ __forceinline__ void gload16(const unsigned short* g, char* l) {
    __builtin_amdgcn_global_load_lds(
        (const __attribute__((address_space(1))) void*)g,
        (__attribute__((address_space(3))) void*)l, 16, 0, 0);
}

// ---- split kernel: f32 -> 3x bf16 planes for x and W, + exact ssum --------
// one block per source row (4096 rows total: x then W); thread = one k-octet.
__global__ __launch_bounds__(256)
void split_kernel(const float* __restrict__ x, const float* __restrict__ W,
                  double* __restrict__ ssum) {
    const int row = blockIdx.x;
    const int tid = threadIdx.x;
    const int mat = row >> 11;          // 0 = x, 1 = W
    const int r   = row & 2047;
    const float* src = (mat ? W : x) + (size_t)r * N_DIM;
    unsigned short* p0 = g_planes + (size_t)(3 * mat) * PLANE
                       + (size_t)r * N_DIM + tid * 8;

    float4 f0 = *(const float4*)(src + tid * 8);
    float4 f1 = *(const float4*)(src + tid * 8 + 4);
    float v[8] = {f0.x, f0.y, f0.z, f0.w, f1.x, f1.y, f1.z, f1.w};
    unsigned h0[8], h1[8], h2[8];
    double s = 0.0;
#pragma unroll
    for (int e = 0; e < 8; ++e) {
        float b;
        h0[e] = bf16_rne(v[e], &b); float r1 = v[e] - b;   // exact residuals
        h1[e] = bf16_rne(r1, &b);   float r2 = r1 - b;
        h2[e] = bf16_rne(r2, &b);
        s += (double)v[e];
    }
    uint4 u;
    u.x = h0[0] | (h0[1] << 16); u.y = h0[2] | (h0[3] << 16);
    u.z = h0[4] | (h0[5] << 16); u.w = h0[6] | (h0[7] << 16);
    *(uint4*)(p0) = u;
    u.x = h1[0] | (h1[1] << 16); u.y = h1[2] | (h1[3] << 16);
    u.z = h1[4] | (h1[5] << 16); u.w = h1[6] | (h1[7] << 16);
    *(uint4*)(p0 + PLANE) = u;
    u.x = h2[0] | (h2[1] << 16); u.y = h2[2] | (h2[3] << 16);
    u.z = h2[4] | (h2[5] << 16); u.w = h2[6] | (h2[7] << 16);
    *(uint4*)(p0 + 2 * PLANE) = u;

    if (mat == 0) {   // spatial row sum (exact f64, fixed order)
        for (int off = 32; off > 0; off >>= 1) s += __shfl_down(s, off, 64);
        __shared__ double wsum[4];
        int lane = tid & 63, wv = tid >> 6;
        if (lane == 0) wsum[wv] = s;
        __syncthreads();
        if (tid == 0) ssum[r] = (wsum[0] + wsum[1]) + (wsum[2] + wsum[3]);
    }
}

// ---- bf16 MFMA wiring probe ------------------------------------------------
__device__ unsigned probe_bf16(float* crefF, int l) {
    int i0 = l >> 2, j0 = (l & 3) << 2;
    for (int jj = 0; jj < 4; ++jj) {
        double s = 0.0;
        for (int k = 0; k < 32; ++k) s += probeA(i0, k) * probeB(k, j0 + jj);
        crefF[i0 * 16 + j0 + jj] = (float)s;      // <= 3872, exact in f32
    }
    __syncthreads();
    short8 af, bf;
#pragma unroll
    for (int j = 0; j < 8; ++j) {
        int k = 8 * (l >> 4) + j;
        af[j] = (short)(__float_as_uint((float)probeA(l & 15, k)) >> 16);
        bf[j] = (short)(__float_as_uint((float)probeB(k, l & 15)) >> 16);
    }
    unsigned win = 0xFFFFFFFFu;
    for (int s = 0; s < 2; ++s) {
        f32x4 d = {0.f, 0.f, 0.f, 0.f};
        d = __builtin_amdgcn_mfma_f32_16x16x32_bf16(s ? bf : af, s ? af : bf,
                                                    d, 0, 0, 0);
        for (int dF = 0; dF < 4; ++dF) {
            float err = 0.f;
#pragma unroll
            for (int r = 0; r < 4; ++r) {
                int ii, jj;
                if (dF == 0)      { ii = 4 * (l >> 4) + r; jj = l & 15; }
                else if (dF == 1) { ii = (l >> 4) + 4 * r; jj = l & 15; }
                else if (dF == 2) { jj = 4 * (l >> 4) + r; ii = l & 15; }
                else              { jj = (l >> 4) + 4 * r; ii = l & 15; }
                err = fmaxf(err, fabsf(d[r] - crefF[ii * 16 + jj]));
            }
            for (int off = 1; off < 64; off <<= 1)
                err = fmaxf(err, __shfl_xor(err, off, 64));
            if (err < 0.5f && win == 0xFFFFFFFFu) win = (unsigned)(s * 4 + dF);
        }
    }
    return win;
}

// ---- GEMM h = x . W^T via 3-way bf16 split (6 MFMA products) ---------------
// v24: counted-vmcnt pipeline (guide T3/T4). R13 PMC: MfmaUtil 22.6% = the
// 43us of MFMA work over 191us -- 75% of each step is wait, because
// __syncthreads() emits s_waitcnt vmcnt(0) before s_barrier, draining the
// just-issued prefetch every step (L2/L3 latency on the critical path).
// Fix: 3 staging buffers, depth-2 prefetch, per-step
//   s_waitcnt vmcnt(6)  (step t landed; t+1's 6 stay IN FLIGHT)
//   raw s_barrier + sched_barrier(0)   (no drain; no compiler reordering)
//   issue stage(t+2); compute slot t%3.
// Hazards: slot written at t was last read at t-1, whose reads retire before
// the step-t barrier (MFMAs consumed them) -> 1 barrier/step. Tail peels to
// vmcnt(0). Explicit __syncthreads() before the epilogue's smem reuse.
#define MF(a, b, c) __builtin_amdgcn_mfma_f32_16x16x32_bf16((a), (b), (c), 0, 0, 0)
#define NSTEP 64
#define BUFB  24576    // bytes per LDS buffer: [A 3x4KB][B 3x4KB]

#define SIX_AB                                                        \
    acc[f][g] = MF(av[0][f], bv[0][g], acc[f][g]);                    \
    acc[f][g] = MF(av[0][f], bv[1][g], acc[f][g]);                    \
    acc[f][g] = MF(av[1][f], bv[0][g], acc[f][g]);                    \
    acc[f][g] = MF(av[1][f], bv[1][g], acc[f][g]);                    \
    acc[f][g] = MF(av[0][f], bv[2][g], acc[f][g]);                    \
    acc[f][g] = MF(av[2][f], bv[0][g], acc[f][g]);

#define SIX_BA                                                        \
    acc[f][g] = MF(bv[0][g], av[0][f], acc[f][g]);                    \
    acc[f][g] = MF(bv[1][g], av[0][f], acc[f][g]);                    \
    acc[f][g] = MF(bv[0][g], av[1][f], acc[f][g]);                    \
    acc[f][g] = MF(bv[1][g], av[1][f], acc[f][g]);                    \
    acc[f][g] = MF(bv[2][g], av[0][f], acc[f][g]);                    \
    acc[f][g] = MF(bv[0][g], av[2][f], acc[f][g]);

#define KLOOP(SIX)                                                    \
    for (int st = 0; st < NSTEP; ++st) {                              \
        if (st < NSTEP - 2) {                                         \
            asm volatile("s_waitcnt vmcnt(6)" ::: "memory");          \
        } else {                                                      \
            asm volatile("s_waitcnt vmcnt(0)" ::: "memory");          \
        }                                                             \
        __builtin_amdgcn_s_barrier();                                 \
        __builtin_amdgcn_sched_barrier(0);                            \
        if (st + 2 < NSTEP) {                                         \
            const int nb = ((st + 2) % 3) * BUFB;                     \
            _Pragma("unroll")                                         \
            for (int ii = 0; ii < 6; ++ii)                            \
                gload16(gsrc[ii] + (st + 2) * 32, smem + nb + ldso[ii]); \
        }                                                             \
        const int cb = (st % 3) * BUFB;                               \
        short8 av[3][2], bv[3][2];                                    \
        _Pragma("unroll")                                             \
        for (int p = 0; p < 3; ++p)                                   \
            _Pragma("unroll")                                         \
            for (int f = 0; f < 2; ++f) {                             \
                av[p][f] = *(const short8*)(smem + cb + p * 4096 + f * 1024 + aoffL); \
                bv[p][f] = *(const short8*)(smem + cb + p * 4096 + f * 1024 + boffL); \
            }                                                         \
        _Pragma("unroll")                                             \
        for (int f = 0; f < 2; ++f)                                   \
            _Pragma("unroll")                                         \
            for (int g = 0; g < 2; ++g) { SIX }                       \
    }

__global__ __launch_bounds__(256, 2)
void gemm_bf16(const float* __restrict__ x, const float* __restrict__ W,
               float* __restrict__ C, double* __restrict__ psum,
               double* __restrict__ psum2) {
    __shared__ __align__(16) char smem[73728];   // 3 x 24KB staging; epi reuse
    const int t    = threadIdx.x;
    const int lane = t & 63;
    const int w    = t >> 6;
    const int wr   = w >> 1, wc = w & 1;

    // XCD-aware slab swizzle: bid&7 = XCD; each XCD gets an 8x16 block slab.
    const int bid = blockIdx.y * 32 + blockIdx.x;
    const int xcd = bid & 7, ii0 = bid >> 3;
    const int bx = (xcd & 3) * 8 + (ii0 & 7);
    const int by = (xcd >> 2) * 16 + (ii0 >> 3);
    const int row0 = by * 64;
    const int col0 = bx * 64;
    const int band = by;

    const unsigned win = probe_bf16((float*)smem, lane);
    __syncthreads();

    if (win <= 7u) {
        const int swp = win >> 2, dF = win & 3;
        int iD[4], jD[4];
#pragma unroll
        for (int r = 0; r < 4; ++r) {
            if (dF == 0)      { iD[r] = 4 * (lane >> 4) + r; jD[r] = lane & 15; }
            else if (dF == 1) { iD[r] = (lane >> 4) + 4 * r; jD[r] = lane & 15; }
            else if (dF == 2) { jD[r] = 4 * (lane >> 4) + r; iD[r] = lane & 15; }
            else              { jD[r] = (lane >> 4) + 4 * r; iD[r] = lane & 15; }
        }

        // staging descriptors: instr i = w + 4*ii; i<12 = A, else B.
        // each instr stages 1KB = 16 rows x 64B of one plane's K-slice.
        const unsigned short* gsrc[6];
        int ldso[6];
#pragma unroll
        for (int ii = 0; ii < 6; ++ii) {
            int i   = w + ii * 4;
            int m   = (i >= 12) ? 1 : 0;
            int r12 = i - 12 * m;
            int p   = r12 >> 2, qq = r12 & 3;
            int grow = (m ? col0 : row0) + qq * 16 + (lane >> 2);
            gsrc[ii] = g_planes + (size_t)(3 * m + p) * PLANE
                     + (size_t)grow * N_DIM + (lane & 3) * 8;
            ldso[ii] = m * 12288 + p * 4096 + qq * 1024;
        }

        // fragment read offsets (linear layout; words 16r+4q)
        const int aoffL = (32 * wr + (lane & 15)) * 64 + (lane >> 4) * 16;
        const int boffL = 12288 + (32 * wc + (lane & 15)) * 64 + (lane >> 4) * 16;

        f32x4 acc[2][2];
#pragma unroll
        for (int f = 0; f < 2; ++f)
#pragma unroll
            for (int g = 0; g < 2; ++g)
                acc[f][g] = (f32x4){0.f, 0.f, 0.f, 0.f};

        // prologue: stage steps 0,1 -> slots 0,1 (12 loads in flight)
#pragma unroll
        for (int ii = 0; ii < 6; ++ii)
            gload16(gsrc[ii], smem + ldso[ii]);
#pragma unroll
        for (int ii = 0; ii < 6; ++ii)
            gload16(gsrc[ii] + 32, smem + BUFB + ldso[ii]);

        if (!swp) { KLOOP(SIX_AB) } else { KLOOP(SIX_BA) }

        __syncthreads();   // all waves done with staging slots before reuse

        // epilogue: direct C store + wave-private BN scatter (layout-agnostic)
        double* region = (double*)(smem + w * 8192);   // 32x32 doubles
#pragma unroll
        for (int f = 0; f < 2; ++f)
#pragma unroll
            for (int g = 0; g < 2; ++g)
#pragma unroll
                for (int r = 0; r < 4; ++r) {
                    region[(16 * f + iD[r]) * 32 + 16 * g + jD[r]] =
                        (double)acc[f][g][r];
                    C[(size_t)(row0 + 32 * wr + 16 * f + iD[r]) * N_DIM
                      + col0 + 32 * wc + 16 * g + jD[r]] = (float)acc[f][g][r];
                }
        // per-wave column partials (same-wave DS ordering; no barrier)
        {
            const int c = lane & 31, half = lane >> 5;
            double s = 0.0, q = 0.0;
#pragma unroll
            for (int r = 0; r < 16; ++r) {
                double v = region[(16 * half + r) * 32 + c];
                s += v;
                q = fma(v, v, q);
            }
            s += __shfl_xor(s, 32, 64);
            q += __shfl_xor(q, 32, 64);
            double* pbuf = (double*)(smem + 65536);    // [4][2][32]
            if (lane < 32) {
                pbuf[(w * 2 + 0) * 32 + c] = s;
                pbuf[(w * 2 + 1) * 32 + c] = q;
            }
        }
        __syncthreads();
        if (t < 64) {
            const int c2 = t & 31, wcc = t >> 5;
            double* pbuf = (double*)(smem + 65536);
            double s = pbuf[(wcc * 2 + 0) * 32 + c2]
                     + pbuf[((wcc + 2) * 2 + 0) * 32 + c2];
            double q = pbuf[(wcc * 2 + 1) * 32 + c2]
                     + pbuf[((wcc + 2) * 2 + 1) * 32 + c2];
            psum [band * N_DIM + col0 + 32 * wcc + c2] = s;
            psum2[band * N_DIM + col0 + 32 * wcc + c2] = q;
        }
    } else {
        // correctness-only fallback (probe failed): naive f64 dot products
        for (int off = t; off < 64 * 64; off += 256) {
            int rr = off >> 6, cc = off & 63;
            const float* xr = x + (size_t)(row0 + rr) * N_DIM;
            const float* wr2 = W + (size_t)(col0 + cc) * N_DIM;
            double s = 0.0;
            for (int k = 0; k < N_DIM; ++k)
                s += (double)xr[k] * (double)wr2[k];
            C[(size_t)(row0 + rr) * N_DIM + col0 + cc] = (float)s;
        }
        __syncthreads();
        if (t < 64) {
            double s = 0.0, q = 0.0;
            for (int rr = 0; rr < 64; ++rr) {
                double v = (double)C[(size_t)(row0 + rr) * N_DIM + col0 + t];
                s += v;
                q = fma(v, v, q);
            }
            psum [band * N_DIM + col0 + t] = s;
            psum2[band * N_DIM + col0 + t] = q;
        }
    }
}

// ---- fused BN-final + BN-apply + temporal-sum + triple LIF + output -------
__global__ __launch_bounds__(256)
void fused_lif_kernel(const float* __restrict__ x, const float* __restrict__ h,
                      const double* __restrict__ psum, const double* __restrict__ psum2,
                      const float* __restrict__ gamma, const float* __restrict__ beta,
                      const double* __restrict__ ssum, float* __restrict__ out) {
    int idx = blockIdx.x * 256 + threadIdx.x;
    int n = idx & (N_DIM - 1);
    int b = idx >> 11;
    // BN scale/shift for this column
    double s = 0.0, s2 = 0.0;
#pragma unroll
    for (int c = 0; c < 32; ++c) {
        s  += psum [c * N_DIM + n];
        s2 += psum2[c * N_DIM + n];
    }
    double mean = s * (1.0 / 2048.0);
    double var  = s2 * (1.0 / 2048.0) - mean * mean;
    double istd = 1.0 / sqrt(var + 1e-5);
    double sc = istd * (double)gamma[n];
    double sh = (double)beta[n] - mean * sc;
    // temporal sum (ascending t, f64)
    float xv[T_DIM];
    double ts = 0.0;
#pragma unroll
    for (int t = 0; t < T_DIM; ++t) {
        xv[t] = x[(size_t)(t * B_DIM + b) * N_DIM + n];
        ts += (double)xv[t];
    }
    double v1 = 0.0, v2 = 0.0, v3 = 0.0;
#pragma unroll
    for (int t = 0; t < T_DIM; ++t) {
        size_t off = (size_t)(t * B_DIM + b) * N_DIM + n;
        double hv = fma((double)h[off], sc, sh);
        v1 = v1 * 0.5 + hv;
        bool s1 = (v1 >= 1.0); if (s1) v1 = 0.0;
        double in2 = s1 ? ssum[t * B_DIM + b] : 0.0;
        v2 = v2 * 0.5 + in2;
        bool s2b = (v2 >= 1.0); if (s2b) v2 = 0.0;
        double in3 = s1 ? ts : 0.0;
        v3 = v3 * 0.5 + in3;
        bool s3 = (v3 >= 1.0); if (s3) v3 = 0.0;
        out[off] = xv[t] + ((s2b && s3) ? 1.0f : 0.0f);
    }
}

extern "C" void kernel_launch(void* const* d_in, const int* in_sizes, int n_in,
                              void* d_out, int out_size, void* d_ws, size_t ws_size,
                              hipStream_t stream) {
    const float* x     = (const float*)d_in[0];   // [16,128,2048]
    const float* W     = (const float*)d_in[1];   // [2048,2048]
    const float* gamma = (const float*)d_in[2];   // [2048]
    const float* beta  = (const float*)d_in[3];   // [2048]
    float* out = (float*)d_out;

    char* ws = (char*)d_ws;
    float*  h     = (float*)(ws + WS_H);
    double* psum  = (double*)(ws + WS_PSUM);
    double* psum2 = (double*)(ws + WS_PSUM2);
    double* ssum  = (double*)(ws + WS_SSUM);

    split_kernel<<<4096, 256, 0, stream>>>(x, W, ssum);
    gemm_bf16<<<dim3(32, 32), 256, 0, stream>>>(x, W, h, psum, psum2);
    fused_lif_kernel<<<(B_DIM * N_DIM) / 256, 256, 0, stream>>>(
        x, h, psum, psum2, gamma, beta, ssum, out);
}

// Round 15
// 271.911 us; speedup vs baseline: 1.1990x; 1.0044x over previous
//
#include <hip/hip_runtime.h>
#include <math.h>

// Problem constants
#define T_DIM 16
#define B_DIM 128
#define N_DIM 2048
#define TB    (T_DIM * B_DIM)   // 2048 rows of the GEMM

// d_ws layout (bytes): h f32 16MB | psum 0.5MB | psum2 0.5MB | ssum 16KB
#define WS_H      0
#define WS_PSUM   16777216
#define WS_PSUM2  17301504
#define WS_SSUM   17825792

typedef __attribute__((ext_vector_type(8))) short short8;
typedef __attribute__((ext_vector_type(4))) float f32x4;

// bf16 split planes: [x0,x1,x2,W0,W1,W2], each [2048][2048] bf16 = 8MB.
// Static device global (module-load allocation; not hipMalloc -> graph-safe).
#define PLANE 4194304ull
__device__ __align__(16) unsigned short g_planes[6ull * PLANE];

// ---- probe helpers (asymmetric integer patterns, exact in bf16/f32) -------
__device__ __forceinline__ double probeA(int m, int k) {
    return (double)((m * 7 + k * 13) % 23 - 11);
}
__device__ __forceinline__ double probeB(int k, int n) {
    return (double)((k * 5 + n * 3) % 19 - 9);
}

// round-to-nearest-even f32 -> bf16; returns bits, writes back-converted f32
__device__ __forceinline__ unsigned bf16_rne(float f, float* back) {
    unsigned u = __float_as_uint(f);
    unsigned r = u + 0x7FFFu + ((u >> 16) & 1u);
    unsigned h = r >> 16;
    *back = __uint_as_float(h << 16);
    return h;
}

// async global->LDS, 16B per lane: LDS dest = wave-uniform base + lane*16.
__device__ __forceinline__ void gload16(const unsigned short* g, char* l) {
    __builtin_amdgcn_global_load_lds(
        (const __attribute__((address_space(1))) void*)g,
        (__attribute__((address_space(3))) void*)l, 16, 0, 0);
}

// ---- split kernel: f32 -> 3x bf16 planes for x and W, + exact ssum --------
// one block per source row (4096 rows total: x then W); thread = one k-octet.
__global__ __launch_bounds__(256)
void split_kernel(const float* __restrict__ x, const float* __restrict__ W,
                  double* __restrict__ ssum) {
    const int row = blockIdx.x;
    const int tid = threadIdx.x;
    const int mat = row >> 11;          // 0 = x, 1 = W
    const int r   = row & 2047;
    const float* src = (mat ? W : x) + (size_t)r * N_DIM;
    unsigned short* p0 = g_planes + (size_t)(3 * mat) * PLANE
                       + (size_t)r * N_DIM + tid * 8;

    float4 f0 = *(const float4*)(src + tid * 8);
    float4 f1 = *(const float4*)(src + tid * 8 + 4);
    float v[8] = {f0.x, f0.y, f0.z, f0.w, f1.x, f1.y, f1.z, f1.w};
    unsigned h0[8], h1[8], h2[8];
    double s = 0.0;
#pragma unroll
    for (int e = 0; e < 8; ++e) {
        float b;
        h0[e] = bf16_rne(v[e], &b); float r1 = v[e] - b;   // exact residuals
        h1[e] = bf16_rne(r1, &b);   float r2 = r1 - b;
        h2[e] = bf16_rne(r2, &b);
        s += (double)v[e];
    }
    uint4 u;
    u.x = h0[0] | (h0[1] << 16); u.y = h0[2] | (h0[3] << 16);
    u.z = h0[4] | (h0[5] << 16); u.w = h0[6] | (h0[7] << 16);
    *(uint4*)(p0) = u;
    u.x = h1[0] | (h1[1] << 16); u.y = h1[2] | (h1[3] << 16);
    u.z = h1[4] | (h1[5] << 16); u.w = h1[6] | (h1[7] << 16);
    *(uint4*)(p0 + PLANE) = u;
    u.x = h2[0] | (h2[1] << 16); u.y = h2[2] | (h2[3] << 16);
    u.z = h2[4] | (h2[5] << 16); u.w = h2[6] | (h2[7] << 16);
    *(uint4*)(p0 + 2 * PLANE) = u;

    if (mat == 0) {   // spatial row sum (exact f64, fixed order)
        for (int off = 32; off > 0; off >>= 1) s += __shfl_down(s, off, 64);
        __shared__ double wsum[4];
        int lane = tid & 63, wv = tid >> 6;
        if (lane == 0) wsum[wv] = s;
        __syncthreads();
        if (tid == 0) ssum[r] = (wsum[0] + wsum[1]) + (wsum[2] + wsum[3]);
    }
}

// ---- bf16 MFMA wiring probe ------------------------------------------------
__device__ unsigned probe_bf16(float* crefF, int l) {
    int i0 = l >> 2, j0 = (l & 3) << 2;
    for (int jj = 0; jj < 4; ++jj) {
        double s = 0.0;
        for (int k = 0; k < 32; ++k) s += probeA(i0, k) * probeB(k, j0 + jj);
        crefF[i0 * 16 + j0 + jj] = (float)s;      // <= 3872, exact in f32
    }
    __syncthreads();
    short8 af, bf;
#pragma unroll
    for (int j = 0; j < 8; ++j) {
        int k = 8 * (l >> 4) + j;
        af[j] = (short)(__float_as_uint((float)probeA(l & 15, k)) >> 16);
        bf[j] = (short)(__float_as_uint((float)probeB(k, l & 15)) >> 16);
    }
    unsigned win = 0xFFFFFFFFu;
    for (int s = 0; s < 2; ++s) {
        f32x4 d = {0.f, 0.f, 0.f, 0.f};
        d = __builtin_amdgcn_mfma_f32_16x16x32_bf16(s ? bf : af, s ? af : bf,
                                                    d, 0, 0, 0);
        for (int dF = 0; dF < 4; ++dF) {
            float err = 0.f;
#pragma unroll
            for (int r = 0; r < 4; ++r) {
                int ii, jj;
                if (dF == 0)      { ii = 4 * (l >> 4) + r; jj = l & 15; }
                else if (dF == 1) { ii = (l >> 4) + 4 * r; jj = l & 15; }
                else if (dF == 2) { jj = 4 * (l >> 4) + r; ii = l & 15; }
                else              { jj = (l >> 4) + 4 * r; ii = l & 15; }
                err = fmaxf(err, fabsf(d[r] - crefF[ii * 16 + jj]));
            }
            for (int off = 1; off < 64; off <<= 1)
                err = fmaxf(err, __shfl_xor(err, off, 64));
            if (err < 0.5f && win == 0xFFFFFFFFu) win = (unsigned)(s * 4 + dF);
        }
    }
    return win;
}

// ---- GEMM h = x . W^T via 3-way bf16 split (6 MFMA products) ---------------
// v25: LDS bank-conflict fix via BOTH-sides XOR swizzle (guide rule #21).
// R14 falsified the barrier-drain theory (counted vmcnt = neutral). Real
// bottleneck per PMC: SQ_LDS_BANK_CONFLICT=12.94M -- tile rows are 64B =
// 16 banks apart, so each k-octet's 16 lanes hit 8 banks = 8-way conflict
// (2.94x) on EVERY ds_read_b128; 96 reads x ~35cy x 2 blk = the ~7200cy
// step wall. MfmaUtil 22.6% x 193us = 43us = exactly the MFMA work: pure
// LDS-read-bound. Fix: slot permutation s_lds = s ^ ((row>>1)&3) spreads
// each group's rows over all 32 banks at 2 lanes/bank (free):
//  - write: gload_lds dest stays LINEAR; global source slot becomes
//    (l&3)^((l>>3)&3)  (qq*16, f*16 row offsets are 0 mod 4 rows).
//  - read: s_lds = (lane>>4) ^ ((lane>>1)&3) folded into aoffL/boffL.
// Decisive counter: BANK_CONFLICT -> <1M. Pipeline/numerics unchanged.
#define MF(a, b, c) __builtin_amdgcn_mfma_f32_16x16x32_bf16((a), (b), (c), 0, 0, 0)
#define NSTEP 64
#define BUFB  24576    // bytes per LDS buffer: [A 3x4KB][B 3x4KB]

#define SIX_AB                                                        \
    acc[f][g] = MF(av[0][f], bv[0][g], acc[f][g]);                    \
    acc[f][g] = MF(av[0][f], bv[1][g], acc[f][g]);                    \
    acc[f][g] = MF(av[1][f], bv[0][g], acc[f][g]);                    \
    acc[f][g] = MF(av[1][f], bv[1][g], acc[f][g]);                    \
    acc[f][g] = MF(av[0][f], bv[2][g], acc[f][g]);                    \
    acc[f][g] = MF(av[2][f], bv[0][g], acc[f][g]);

#define SIX_BA                                                        \
    acc[f][g] = MF(bv[0][g], av[0][f], acc[f][g]);                    \
    acc[f][g] = MF(bv[1][g], av[0][f], acc[f][g]);                    \
    acc[f][g] = MF(bv[0][g], av[1][f], acc[f][g]);                    \
    acc[f][g] = MF(bv[1][g], av[1][f], acc[f][g]);                    \
    acc[f][g] = MF(bv[2][g], av[0][f], acc[f][g]);                    \
    acc[f][g] = MF(bv[0][g], av[2][f], acc[f][g]);

#define KLOOP(SIX)                                                    \
    for (int st = 0; st < NSTEP; ++st) {                              \
        if (st < NSTEP - 2) {                                         \
            asm volatile("s_waitcnt vmcnt(6)" ::: "memory");          \
        } else {                                                      \
            asm volatile("s_waitcnt vmcnt(0)" ::: "memory");          \
        }                                                             \
        __builtin_amdgcn_s_barrier();                                 \
        __builtin_amdgcn_sched_barrier(0);                            \
        if (st + 2 < NSTEP) {                                         \
            const int nb = ((st + 2) % 3) * BUFB;                     \
            _Pragma("unroll")                                         \
            for (int ii = 0; ii < 6; ++ii)                            \
                gload16(gsrc[ii] + (st + 2) * 32, smem + nb + ldso[ii]); \
        }                                                             \
        const int cb = (st % 3) * BUFB;                               \
        short8 av[3][2], bv[3][2];                                    \
        _Pragma("unroll")                                             \
        for (int p = 0; p < 3; ++p)                                   \
            _Pragma("unroll")                                         \
            for (int f = 0; f < 2; ++f) {                             \
                av[p][f] = *(const short8*)(smem + cb + p * 4096 + f * 1024 + aoffL); \
                bv[p][f] = *(const short8*)(smem + cb + p * 4096 + f * 1024 + boffL); \
            }                                                         \
        _Pragma("unroll")                                             \
        for (int f = 0; f < 2; ++f)                                   \
            _Pragma("unroll")                                         \
            for (int g = 0; g < 2; ++g) { SIX }                       \
    }

__global__ __launch_bounds__(256, 2)
void gemm_bf16(const float* __restrict__ x, const float* __restrict__ W,
               float* __restrict__ C, double* __restrict__ psum,
               double* __restrict__ psum2) {
    __shared__ __align__(16) char smem[73728];   // 3 x 24KB staging; epi reuse
    const int t    = threadIdx.x;
    const int lane = t & 63;
    const int w    = t >> 6;
    const int wr   = w >> 1, wc = w & 1;

    // XCD-aware slab swizzle: bid&7 = XCD; each XCD gets an 8x16 block slab.
    const int bid = blockIdx.y * 32 + blockIdx.x;
    const int xcd = bid & 7, ii0 = bid >> 3;
    const int bx = (xcd & 3) * 8 + (ii0 & 7);
    const int by = (xcd >> 2) * 16 + (ii0 >> 3);
    const int row0 = by * 64;
    const int col0 = bx * 64;
    const int band = by;

    const unsigned win = probe_bf16((float*)smem, lane);
    __syncthreads();

    if (win <= 7u) {
        const int swp = win >> 2, dF = win & 3;
        int iD[4], jD[4];
#pragma unroll
        for (int r = 0; r < 4; ++r) {
            if (dF == 0)      { iD[r] = 4 * (lane >> 4) + r; jD[r] = lane & 15; }
            else if (dF == 1) { iD[r] = (lane >> 4) + 4 * r; jD[r] = lane & 15; }
            else if (dF == 2) { jD[r] = 4 * (lane >> 4) + r; iD[r] = lane & 15; }
            else              { jD[r] = (lane >> 4) + 4 * r; iD[r] = lane & 15; }
        }

        // staging descriptors: instr i = w + 4*ii; i<12 = A, else B.
        // each instr stages 1KB = 16 rows x 64B of one plane's K-slice.
        // BANK SWIZZLE (write side): LDS dest linear; global source slot
        // = (l&3) ^ ((l>>3)&3), so LDS slot s at row r holds logical slot
        // s ^ ((r>>1)&3).
        const unsigned short* gsrc[6];
        int ldso[6];
        const int sslot = ((lane & 3) ^ ((lane >> 3) & 3)) * 8;
#pragma unroll
        for (int ii = 0; ii < 6; ++ii) {
            int i   = w + ii * 4;
            int m   = (i >= 12) ? 1 : 0;
            int r12 = i - 12 * m;
            int p   = r12 >> 2, qq = r12 & 3;
            int grow = (m ? col0 : row0) + qq * 16 + (lane >> 2);
            gsrc[ii] = g_planes + (size_t)(3 * m + p) * PLANE
                     + (size_t)grow * N_DIM + sslot;
            ldso[ii] = m * 12288 + p * 4096 + qq * 1024;
        }

        // fragment read offsets, swizzle-matched: s_lds = (lane>>4)^((lane>>1)&3)
        const int rslot = ((lane >> 4) ^ ((lane >> 1) & 3)) * 16;
        const int aoffL = (32 * wr + (lane & 15)) * 64 + rslot;
        const int boffL = 12288 + (32 * wc + (lane & 15)) * 64 + rslot;

        f32x4 acc[2][2];
#pragma unroll
        for (int f = 0; f < 2; ++f)
#pragma unroll
            for (int g = 0; g < 2; ++g)
                acc[f][g] = (f32x4){0.f, 0.f, 0.f, 0.f};

        // prologue: stage steps 0,1 -> slots 0,1 (12 loads in flight)
#pragma unroll
        for (int ii = 0; ii < 6; ++ii)
            gload16(gsrc[ii], smem + ldso[ii]);
#pragma unroll
        for (int ii = 0; ii < 6; ++ii)
            gload16(gsrc[ii] + 32, smem + BUFB + ldso[ii]);

        if (!swp) { KLOOP(SIX_AB) } else { KLOOP(SIX_BA) }

        __syncthreads();   // all waves done with staging slots before reuse

        // epilogue: direct C store + wave-private BN scatter (layout-agnostic)
        double* region = (double*)(smem + w * 8192);   // 32x32 doubles
#pragma unroll
        for (int f = 0; f < 2; ++f)
#pragma unroll
            for (int g = 0; g < 2; ++g)
#pragma unroll
                for (int r = 0; r < 4; ++r) {
                    region[(16 * f + iD[r]) * 32 + 16 * g + jD[r]] =
                        (double)acc[f][g][r];
                    C[(size_t)(row0 + 32 * wr + 16 * f + iD[r]) * N_DIM
                      + col0 + 32 * wc + 16 * g + jD[r]] = (float)acc[f][g][r];
                }
        // per-wave column partials (same-wave DS ordering; no barrier)
        {
            const int c = lane & 31, half = lane >> 5;
            double s = 0.0, q = 0.0;
#pragma unroll
            for (int r = 0; r < 16; ++r) {
                double v = region[(16 * half + r) * 32 + c];
                s += v;
                q = fma(v, v, q);
            }
            s += __shfl_xor(s, 32, 64);
            q += __shfl_xor(q, 32, 64);
            double* pbuf = (double*)(smem + 65536);    // [4][2][32]
            if (lane < 32) {
                pbuf[(w * 2 + 0) * 32 + c] = s;
                pbuf[(w * 2 + 1) * 32 + c] = q;
            }
        }
        __syncthreads();
        if (t < 64) {
            const int c2 = t & 31, wcc = t >> 5;
            double* pbuf = (double*)(smem + 65536);
            double s = pbuf[(wcc * 2 + 0) * 32 + c2]
                     + pbuf[((wcc + 2) * 2 + 0) * 32 + c2];
            double q = pbuf[(wcc * 2 + 1) * 32 + c2]
                     + pbuf[((wcc + 2) * 2 + 1) * 32 + c2];
            psum [band * N_DIM + col0 + 32 * wcc + c2] = s;
            psum2[band * N_DIM + col0 + 32 * wcc + c2] = q;
        }
    } else {
        // correctness-only fallback (probe failed): naive f64 dot products
        for (int off = t; off < 64 * 64; off += 256) {
            int rr = off >> 6, cc = off & 63;
            const float* xr = x + (size_t)(row0 + rr) * N_DIM;
            const float* wr2 = W + (size_t)(col0 + cc) * N_DIM;
            double s = 0.0;
            for (int k = 0; k < N_DIM; ++k)
                s += (double)xr[k] * (double)wr2[k];
            C[(size_t)(row0 + rr) * N_DIM + col0 + cc] = (float)s;
        }
        __syncthreads();
        if (t < 64) {
            double s = 0.0, q = 0.0;
            for (int rr = 0; rr < 64; ++rr) {
                double v = (double)C[(size_t)(row0 + rr) * N_DIM + col0 + t];
                s += v;
                q = fma(v, v, q);
            }
            psum [band * N_DIM + col0 + t] = s;
            psum2[band * N_DIM + col0 + t] = q;
        }
    }
}

// ---- fused BN-final + BN-apply + temporal-sum + triple LIF + output -------
__global__ __launch_bounds__(256)
void fused_lif_kernel(const float* __restrict__ x, const float* __restrict__ h,
                      const double* __restrict__ psum, const double* __restrict__ psum2,
                      const float* __restrict__ gamma, const float* __restrict__ beta,
                      const double* __restrict__ ssum, float* __restrict__ out) {
    int idx = blockIdx.x * 256 + threadIdx.x;
    int n = idx & (N_DIM - 1);
    int b = idx >> 11;
    // BN scale/shift for this column
    double s = 0.0, s2 = 0.0;
#pragma unroll
    for (int c = 0; c < 32; ++c) {
        s  += psum [c * N_DIM + n];
        s2 += psum2[c * N_DIM + n];
    }
    double mean = s * (1.0 / 2048.0);
    double var  = s2 * (1.0 / 2048.0) - mean * mean;
    double istd = 1.0 / sqrt(var + 1e-5);
    double sc = istd * (double)gamma[n];
    double sh = (double)beta[n] - mean * sc;
    // temporal sum (ascending t, f64)
    float xv[T_DIM];
    double ts = 0.0;
#pragma unroll
    for (int t = 0; t < T_DIM; ++t) {
        xv[t] = x[(size_t)(t * B_DIM + b) * N_DIM + n];
        ts += (double)xv[t];
    }
    double v1 = 0.0, v2 = 0.0, v3 = 0.0;
#pragma unroll
    for (int t = 0; t < T_DIM; ++t) {
        size_t off = (size_t)(t * B_DIM + b) * N_DIM + n;
        double hv = fma((double)h[off], sc, sh);
        v1 = v1 * 0.5 + hv;
        bool s1 = (v1 >= 1.0); if (s1) v1 = 0.0;
        double in2 = s1 ? ssum[t * B_DIM + b] : 0.0;
        v2 = v2 * 0.5 + in2;
        bool s2b = (v2 >= 1.0); if (s2b) v2 = 0.0;
        double in3 = s1 ? ts : 0.0;
        v3 = v3 * 0.5 + in3;
        bool s3 = (v3 >= 1.0); if (s3) v3 = 0.0;
        out[off] = xv[t] + ((s2b && s3) ? 1.0f : 0.0f);
    }
}

extern "C" void kernel_launch(void* const* d_in, const int* in_sizes, int n_in,
                              void* d_out, int out_size, void* d_ws, size_t ws_size,
                              hipStream_t stream) {
    const float* x     = (const float*)d_in[0];   // [16,128,2048]
    const float* W     = (const float*)d_in[1];   // [2048,2048]
    const float* gamma = (const float*)d_in[2];   // [2048]
    const float* beta  = (const float*)d_in[3];   // [2048]
    float* out = (float*)d_out;

    char* ws = (char*)d_ws;
    float*  h     = (float*)(ws + WS_H);
    double* psum  = (double*)(ws + WS_PSUM);
    double* psum2 = (double*)(ws + WS_PSUM2);
    double* ssum  = (double*)(ws + WS_SSUM);

    split_kernel<<<4096, 256, 0, stream>>>(x, W, ssum);
    gemm_bf16<<<dim3(32, 32), 256, 0, stream>>>(x, W, h, psum, psum2);
    fused_lif_kernel<<<(B_DIM * N_DIM) / 256, 256, 0, stream>>>(
        x, h, psum, psum2, gamma, beta, ssum, out);
}

// Round 16
// 236.021 us; speedup vs baseline: 1.3813x; 1.1521x over previous
//
#include <hip/hip_runtime.h>
#include <math.h>

// Problem constants
#define T_DIM 16
#define B_DIM 128
#define N_DIM 2048
#define TB    (T_DIM * B_DIM)   // 2048 rows of the GEMM

// d_ws layout (bytes): h f32 16MB | psum 256KB | psum2 256KB | ssum 16KB
#define WS_H      0
#define WS_PSUM   16777216
#define WS_PSUM2  17301504
#define WS_SSUM   17825792

typedef __attribute__((ext_vector_type(8))) short short8;
typedef __attribute__((ext_vector_type(4))) float f32x4;

// bf16 split planes: [x0,x1,x2,W0,W1,W2], each [2048][2048] bf16 = 8MB.
// Static device global (module-load allocation; not hipMalloc -> graph-safe).
#define PLANE 4194304ull
__device__ __align__(16) unsigned short g_planes[6ull * PLANE];

// ---- probe helpers (asymmetric integer patterns, exact in bf16/f32) -------
__device__ __forceinline__ double probeA(int m, int k) {
    return (double)((m * 7 + k * 13) % 23 - 11);
}
__device__ __forceinline__ double probeB(int k, int n) {
    return (double)((k * 5 + n * 3) % 19 - 9);
}

// round-to-nearest-even f32 -> bf16; returns bits, writes back-converted f32
__device__ __forceinline__ unsigned bf16_rne(float f, float* back) {
    unsigned u = __float_as_uint(f);
    unsigned r = u + 0x7FFFu + ((u >> 16) & 1u);
    unsigned h = r >> 16;
    *back = __uint_as_float(h << 16);
    return h;
}

// async global->LDS, 16B per lane: LDS dest = wave-uniform base + lane*16.
__device__ __forceinline__ void gload16(const unsigned short* g, char* l) {
    __builtin_amdgcn_global_load_lds(
        (const __attribute__((address_space(1))) void*)g,
        (__attribute__((address_space(3))) void*)l, 16, 0, 0);
}

// ---- split kernel: f32 -> 3x bf16 planes for x and W, + exact ssum --------
// one block per source row (4096 rows total: x then W); thread = one k-octet.
__global__ __launch_bounds__(256)
void split_kernel(const float* __restrict__ x, const float* __restrict__ W,
                  double* __restrict__ ssum) {
    const int row = blockIdx.x;
    const int tid = threadIdx.x;
    const int mat = row >> 11;          // 0 = x, 1 = W
    const int r   = row & 2047;
    const float* src = (mat ? W : x) + (size_t)r * N_DIM;
    unsigned short* p0 = g_planes + (size_t)(3 * mat) * PLANE
                       + (size_t)r * N_DIM + tid * 8;

    float4 f0 = *(const float4*)(src + tid * 8);
    float4 f1 = *(const float4*)(src + tid * 8 + 4);
    float v[8] = {f0.x, f0.y, f0.z, f0.w, f1.x, f1.y, f1.z, f1.w};
    unsigned h0[8], h1[8], h2[8];
    double s = 0.0;
#pragma unroll
    for (int e = 0; e < 8; ++e) {
        float b;
        h0[e] = bf16_rne(v[e], &b); float r1 = v[e] - b;   // exact residuals
        h1[e] = bf16_rne(r1, &b);   float r2 = r1 - b;
        h2[e] = bf16_rne(r2, &b);
        s += (double)v[e];
    }
    uint4 u;
    u.x = h0[0] | (h0[1] << 16); u.y = h0[2] | (h0[3] << 16);
    u.z = h0[4] | (h0[5] << 16); u.w = h0[6] | (h0[7] << 16);
    *(uint4*)(p0) = u;
    u.x = h1[0] | (h1[1] << 16); u.y = h1[2] | (h1[3] << 16);
    u.z = h1[4] | (h1[5] << 16); u.w = h1[6] | (h1[7] << 16);
    *(uint4*)(p0 + PLANE) = u;
    u.x = h2[0] | (h2[1] << 16); u.y = h2[2] | (h2[3] << 16);
    u.z = h2[4] | (h2[5] << 16); u.w = h2[6] | (h2[7] << 16);
    *(uint4*)(p0 + 2 * PLANE) = u;

    if (mat == 0) {   // spatial row sum (exact f64, fixed order)
        for (int off = 32; off > 0; off >>= 1) s += __shfl_down(s, off, 64);
        __shared__ double wsum[4];
        int lane = tid & 63, wv = tid >> 6;
        if (lane == 0) wsum[wv] = s;
        __syncthreads();
        if (tid == 0) ssum[r] = (wsum[0] + wsum[1]) + (wsum[2] + wsum[3]);
    }
}

// ---- bf16 MFMA wiring probe ------------------------------------------------
__device__ unsigned probe_bf16(float* crefF, int l) {
    int i0 = l >> 2, j0 = (l & 3) << 2;
    for (int jj = 0; jj < 4; ++jj) {
        double s = 0.0;
        for (int k = 0; k < 32; ++k) s += probeA(i0, k) * probeB(k, j0 + jj);
        crefF[i0 * 16 + j0 + jj] = (float)s;      // <= 3872, exact in f32
    }
    __syncthreads();
    short8 af, bf;
#pragma unroll
    for (int j = 0; j < 8; ++j) {
        int k = 8 * (l >> 4) + j;
        af[j] = (short)(__float_as_uint((float)probeA(l & 15, k)) >> 16);
        bf[j] = (short)(__float_as_uint((float)probeB(k, l & 15)) >> 16);
    }
    unsigned win = 0xFFFFFFFFu;
    for (int s = 0; s < 2; ++s) {
        f32x4 d = {0.f, 0.f, 0.f, 0.f};
        d = __builtin_amdgcn_mfma_f32_16x16x32_bf16(s ? bf : af, s ? af : bf,
                                                    d, 0, 0, 0);
        for (int dF = 0; dF < 4; ++dF) {
            float err = 0.f;
#pragma unroll
            for (int r = 0; r < 4; ++r) {
                int ii, jj;
                if (dF == 0)      { ii = 4 * (l >> 4) + r; jj = l & 15; }
                else if (dF == 1) { ii = (l >> 4) + 4 * r; jj = l & 15; }
                else if (dF == 2) { jj = 4 * (l >> 4) + r; ii = l & 15; }
                else              { jj = (l >> 4) + 4 * r; ii = l & 15; }
                err = fmaxf(err, fabsf(d[r] - crefF[ii * 16 + jj]));
            }
            for (int off = 1; off < 64; off <<= 1)
                err = fmaxf(err, __shfl_xor(err, off, 64));
            if (err < 0.5f && win == 0xFFFFFFFFu) win = (unsigned)(s * 4 + dF);
        }
    }
    return win;
}

// ---- GEMM h = x . W^T via 3-way bf16 split (6 MFMA products) ---------------
// v26: 4 waves/SIMD via 128x64 block (8 waves, 512 thr), per-wave code
// unchanged. Evidence chain: R14 (counted vmcnt) neutral; R15 (conflict fix,
// 12.9M->352K) neutral -- every within-step micro-cost exonerated. Per-SIMD
// arithmetic: 256 wave-steps x ~1780cy wall vs ~400cy work = latency chain
// (barrier -> ds_read ~150cy -> 6-deep MFMA chains) covered by only ONE
// partner wave (2 blocks/CU x 4 waves = 2/SIMD, LDS-limited). Keeping LDS
// at 73.7KB but doubling waves/block -> 16 waves/CU = 4/SIMD. Staging:
// waves 0-3 stage A (6 x 1KB), waves 4-7 stage B (3 x 1KB); 2 buffers,
// depth-1 prefetch issued POST-barrier (write-after-read safe; R14 proved
// counted-vs-drain neutral). Swizzle carried over verbatim.
// Decisive: if dur ~unchanged, the limit is a per-CU shared resource
// (LDS pipe / DMA) -> structure at ceiling.
#define MF(a, b, c) __builtin_amdgcn_mfma_f32_16x16x32_bf16((a), (b), (c), 0, 0, 0)
#define NSTEP 64
#define BUFB  36864    // bytes per LDS buffer: [A 3x8KB][B 3x4KB]

#define SIX_AB                                                        \
    acc[f][g] = MF(av[0][f], bv[0][g], acc[f][g]);                    \
    acc[f][g] = MF(av[0][f], bv[1][g], acc[f][g]);                    \
    acc[f][g] = MF(av[1][f], bv[0][g], acc[f][g]);                    \
    acc[f][g] = MF(av[1][f], bv[1][g], acc[f][g]);                    \
    acc[f][g] = MF(av[0][f], bv[2][g], acc[f][g]);                    \
    acc[f][g] = MF(av[2][f], bv[0][g], acc[f][g]);

#define SIX_BA                                                        \
    acc[f][g] = MF(bv[0][g], av[0][f], acc[f][g]);                    \
    acc[f][g] = MF(bv[1][g], av[0][f], acc[f][g]);                    \
    acc[f][g] = MF(bv[0][g], av[1][f], acc[f][g]);                    \
    acc[f][g] = MF(bv[1][g], av[1][f], acc[f][g]);                    \
    acc[f][g] = MF(bv[2][g], av[0][f], acc[f][g]);                    \
    acc[f][g] = MF(bv[0][g], av[2][f], acc[f][g]);

#define KLOOP(SIX)                                                    \
    for (int st = 0; st < NSTEP; ++st) {                              \
        asm volatile("s_waitcnt vmcnt(0)" ::: "memory");              \
        __builtin_amdgcn_s_barrier();                                 \
        __builtin_amdgcn_sched_barrier(0);                            \
        if (st + 1 < NSTEP) {                                         \
            const int nb = ((st + 1) & 1) * BUFB;                     \
            _Pragma("unroll")                                         \
            for (int ii = 0; ii < 6; ++ii)                            \
                if (ii < nst)                                         \
                    gload16(gsrc[ii] + (st + 1) * 32, smem + nb + ldso[ii]); \
        }                                                             \
        const int cb = (st & 1) * BUFB;                               \
        short8 av[3][2], bv[3][2];                                    \
        _Pragma("unroll")                                             \
        for (int p = 0; p < 3; ++p)                                   \
            _Pragma("unroll")                                         \
            for (int f = 0; f < 2; ++f) {                             \
                av[p][f] = *(const short8*)(smem + cb + p * 8192 + f * 1024 + aoffL); \
                bv[p][f] = *(const short8*)(smem + cb + 24576 + p * 4096 + f * 1024 + boffL); \
            }                                                         \
        _Pragma("unroll")                                             \
        for (int f = 0; f < 2; ++f)                                   \
            _Pragma("unroll")                                         \
            for (int g = 0; g < 2; ++g) { SIX }                       \
    }

__global__ __launch_bounds__(512, 2)
void gemm_bf16(const float* __restrict__ x, const float* __restrict__ W,
               float* __restrict__ C, double* __restrict__ psum,
               double* __restrict__ psum2) {
    __shared__ __align__(16) char smem[73728];   // 2 x 36KB staging; epi reuse
    const int t    = threadIdx.x;
    const int lane = t & 63;
    const int w    = t >> 6;          // 0..7
    const int wr   = w >> 1, wc = w & 1;

    // XCD-aware slab swizzle: bid&7 = XCD; each XCD gets an 8x8 block slab.
    const int bid = blockIdx.y * 32 + blockIdx.x;   // grid 32 x 16
    const int xcd = bid & 7, ii0 = bid >> 3;        // ii0 0..63
    const int bx = (xcd & 3) * 8 + (ii0 & 7);       // 0..31 (64-col tiles)
    const int by = (xcd >> 2) * 8 + (ii0 >> 3);     // 0..15 (128-row tiles)
    const int row0 = by * 128;
    const int col0 = bx * 64;
    const int band = by;

    const unsigned win = probe_bf16((float*)smem, lane);
    __syncthreads();

    if (win <= 7u) {
        const int swp = win >> 2, dF = win & 3;
        int iD[4], jD[4];
#pragma unroll
        for (int r = 0; r < 4; ++r) {
            if (dF == 0)      { iD[r] = 4 * (lane >> 4) + r; jD[r] = lane & 15; }
            else if (dF == 1) { iD[r] = (lane >> 4) + 4 * r; jD[r] = lane & 15; }
            else if (dF == 2) { jD[r] = 4 * (lane >> 4) + r; iD[r] = lane & 15; }
            else              { jD[r] = (lane >> 4) + 4 * r; iD[r] = lane & 15; }
        }

        // staging: waves 0-3 stage A (6 x 1KB: plane p=j>>3, rowq q=j&7),
        // waves 4-7 stage B (3 x 1KB: p=j>>2, q=j&3). LDS dest linear;
        // global source slot pre-swizzled: (l&3)^((l>>3)&3).
        const int sslot = ((lane & 3) ^ ((lane >> 3) & 3)) * 8;
        int nst;
        const unsigned short* gsrc[6];
        int ldso[6];
        if (w < 4) {
            nst = 6;
#pragma unroll
            for (int jj = 0; jj < 6; ++jj) {
                int j = w * 6 + jj;            // 0..23
                int p = j >> 3, q = j & 7;
                int grow = row0 + q * 16 + (lane >> 2);
                gsrc[jj] = g_planes + (size_t)p * PLANE
                         + (size_t)grow * N_DIM + sslot;
                ldso[jj] = p * 8192 + q * 1024;
            }
        } else {
            nst = 3;
#pragma unroll
            for (int jj = 0; jj < 3; ++jj) {
                int j = (w - 4) * 3 + jj;      // 0..11
                int p = j >> 2, q = j & 3;
                int grow = col0 + q * 16 + (lane >> 2);
                gsrc[jj] = g_planes + (size_t)(3 + p) * PLANE
                         + (size_t)grow * N_DIM + sslot;
                ldso[jj] = 24576 + p * 4096 + q * 1024;
            }
#pragma unroll
            for (int jj = 3; jj < 6; ++jj) { gsrc[jj] = gsrc[0]; ldso[jj] = ldso[0]; }
        }

        // fragment read offsets, swizzle-matched: slot = (lane>>4)^((lane>>1)&3)
        const int rslot = ((lane >> 4) ^ ((lane >> 1) & 3)) * 16;
        const int aoffL = 2048 * wr + (lane & 15) * 64 + rslot;
        const int boffL = 2048 * wc + (lane & 15) * 64 + rslot;

        f32x4 acc[2][2];
#pragma unroll
        for (int f = 0; f < 2; ++f)
#pragma unroll
            for (int g = 0; g < 2; ++g)
                acc[f][g] = (f32x4){0.f, 0.f, 0.f, 0.f};

        // prologue: stage step 0 -> buf0
#pragma unroll
        for (int ii = 0; ii < 6; ++ii)
            if (ii < nst) gload16(gsrc[ii], smem + ldso[ii]);

        if (!swp) { KLOOP(SIX_AB) } else { KLOOP(SIX_BA) }

        __syncthreads();   // all waves done with staging slots before reuse

        // epilogue: direct C store + wave-private BN scatter (layout-agnostic)
        double* region = (double*)(smem + w * 8192);   // 32x32 doubles
#pragma unroll
        for (int f = 0; f < 2; ++f)
#pragma unroll
            for (int g = 0; g < 2; ++g)
#pragma unroll
                for (int r = 0; r < 4; ++r) {
                    region[(16 * f + iD[r]) * 32 + 16 * g + jD[r]] =
                        (double)acc[f][g][r];
                    C[(size_t)(row0 + 32 * wr + 16 * f + iD[r]) * N_DIM
                      + col0 + 32 * wc + 16 * g + jD[r]] = (float)acc[f][g][r];
                }
        // per-wave column partials (same-wave DS ordering; no barrier)
        {
            const int c = lane & 31, half = lane >> 5;
            double s = 0.0, q = 0.0;
#pragma unroll
            for (int r = 0; r < 16; ++r) {
                double v = region[(16 * half + r) * 32 + c];
                s += v;
                q = fma(v, v, q);
            }
            s += __shfl_xor(s, 32, 64);
            q += __shfl_xor(q, 32, 64);
            double* pbuf = (double*)(smem + 65536);    // [8][2][32]
            if (lane < 32) {
                pbuf[(w * 2 + 0) * 32 + c] = s;
                pbuf[(w * 2 + 1) * 32 + c] = q;
            }
        }
        __syncthreads();
        if (t < 64) {
            const int c = t, hc = c >> 5, cc = c & 31;
            double* pbuf = (double*)(smem + 65536);
            double s = 0.0, q = 0.0;
#pragma unroll
            for (int wr4 = 0; wr4 < 4; ++wr4) {
                int ww = wr4 * 2 + hc;
                s += pbuf[(ww * 2 + 0) * 32 + cc];
                q += pbuf[(ww * 2 + 1) * 32 + cc];
            }
            psum [band * N_DIM + col0 + c] = s;
            psum2[band * N_DIM + col0 + c] = q;
        }
    } else {
        // correctness-only fallback (probe failed): naive f64 dot products
        for (int off = t; off < 128 * 64; off += 512) {
            int rr = off >> 6, cc = off & 63;
            const float* xr = x + (size_t)(row0 + rr) * N_DIM;
            const float* wr2 = W + (size_t)(col0 + cc) * N_DIM;
            double s = 0.0;
            for (int k = 0; k < N_DIM; ++k)
                s += (double)xr[k] * (double)wr2[k];
            C[(size_t)(row0 + rr) * N_DIM + col0 + cc] = (float)s;
        }
        __syncthreads();
        if (t < 64) {
            double s = 0.0, q = 0.0;
            for (int rr = 0; rr < 128; ++rr) {
                double v = (double)C[(size_t)(row0 + rr) * N_DIM + col0 + t];
                s += v;
                q = fma(v, v, q);
            }
            psum [band * N_DIM + col0 + t] = s;
            psum2[band * N_DIM + col0 + t] = q;
        }
    }
}

// ---- fused BN-final + BN-apply + temporal-sum + triple LIF + output -------
__global__ __launch_bounds__(256)
void fused_lif_kernel(const float* __restrict__ x, const float* __restrict__ h,
                      const double* __restrict__ psum, const double* __restrict__ psum2,
                      const float* __restrict__ gamma, const float* __restrict__ beta,
                      const double* __restrict__ ssum, float* __restrict__ out) {
    int idx = blockIdx.x * 256 + threadIdx.x;
    int n = idx & (N_DIM - 1);
    int b = idx >> 11;
    // BN scale/shift for this column (16 bands of 128 rows)
    double s = 0.0, s2 = 0.0;
#pragma unroll
    for (int c = 0; c < 16; ++c) {
        s  += psum [c * N_DIM + n];
        s2 += psum2[c * N_DIM + n];
    }
    double mean = s * (1.0 / 2048.0);
    double var  = s2 * (1.0 / 2048.0) - mean * mean;
    double istd = 1.0 / sqrt(var + 1e-5);
    double sc = istd * (double)gamma[n];
    double sh = (double)beta[n] - mean * sc;
    // temporal sum (ascending t, f64)
    float xv[T_DIM];
    double ts = 0.0;
#pragma unroll
    for (int t = 0; t < T_DIM; ++t) {
        xv[t] = x[(size_t)(t * B_DIM + b) * N_DIM + n];
        ts += (double)xv[t];
    }
    double v1 = 0.0, v2 = 0.0, v3 = 0.0;
#pragma unroll
    for (int t = 0; t < T_DIM; ++t) {
        size_t off = (size_t)(t * B_DIM + b) * N_DIM + n;
        double hv = fma((double)h[off], sc, sh);
        v1 = v1 * 0.5 + hv;
        bool s1 = (v1 >= 1.0); if (s1) v1 = 0.0;
        double in2 = s1 ? ssum[t * B_DIM + b] : 0.0;
        v2 = v2 * 0.5 + in2;
        bool s2b = (v2 >= 1.0); if (s2b) v2 = 0.0;
        double in3 = s1 ? ts : 0.0;
        v3 = v3 * 0.5 + in3;
        bool s3 = (v3 >= 1.0); if (s3) v3 = 0.0;
        out[off] = xv[t] + ((s2b && s3) ? 1.0f : 0.0f);
    }
}

extern "C" void kernel_launch(void* const* d_in, const int* in_sizes, int n_in,
                              void* d_out, int out_size, void* d_ws, size_t ws_size,
                              hipStream_t stream) {
    const float* x     = (const float*)d_in[0];   // [16,128,2048]
    const float* W     = (const float*)d_in[1];   // [2048,2048]
    const float* gamma = (const float*)d_in[2];   // [2048]
    const float* beta  = (const float*)d_in[3];   // [2048]
    float* out = (float*)d_out;

    char* ws = (char*)d_ws;
    float*  h     = (float*)(ws + WS_H);
    double* psum  = (double*)(ws + WS_PSUM);
    double* psum2 = (double*)(ws + WS_PSUM2);
    double* ssum  = (double*)(ws + WS_SSUM);

    split_kernel<<<4096, 256, 0, stream>>>(x, W, ssum);
    gemm_bf16<<<dim3(32, 16), 512, 0, stream>>>(x, W, h, psum, psum2);
    fused_lif_kernel<<<(B_DIM * N_DIM) / 256, 256, 0, stream>>>(
        x, h, psum, psum2, gamma, beta, ssum, out);
}